// Round 10
// baseline (670.043 us; speedup 1.0000x reference)
//
#include <hip/hip_runtime.h>
#include <math.h>

// ---------------------------------------------------------------------------
// Model dims: BS=1024 T=10 H=256 C=128 E=50 SEQ=50 V=50000 NREG=1
// R9 = DIFFERENTIAL PROBE: bit-exact resubmit of the R2 source (ran cleanly
//   twice: 762us R2, 667us R4). R4-family source hit "container failed twice"
//   3/3 times (R6/R8/R9) incl. with restored ws footprint (R8) — this control
//   separates degraded-infra from source-induced container death.
//     (a) textcnn LDS alias sx/sc3 -> 13.3KB/wave, 1 wave/block
//     (b) GRU fused to ONE kernel, bf16 MFMA, gate-interleaved N-tiles
//     (c) k_gi bf16 MFMA (m stored bf16 by k_merge)
// ---------------------------------------------------------------------------

typedef unsigned short u16;
typedef __attribute__((ext_vector_type(8))) short short8v;   // 8 bf16 = 4 VGPR
typedef __attribute__((ext_vector_type(4))) float float4v;
#define MFMA16 __builtin_amdgcn_mfma_f32_16x16x32_bf16

__device__ inline u16 f2bf(float f) {
  unsigned u = __float_as_uint(f);
  u += 0x7FFFu + ((u >> 16) & 1u);            // RNE
  return (u16)(u >> 16);
}

__global__ __launch_bounds__(256) void k_zero(float* __restrict__ p, int n) {
  int i = blockIdx.x * 256 + threadIdx.x;
  if (i < n) p[i] = 0.f;
}

// conv3 weights [c=128][e=50][kk=3] -> frag-linear B: [kt=6][nt=8][lane=64][j=8]
__global__ __launch_bounds__(256) void k_repb3(const float* __restrict__ w3,
                                               u16* __restrict__ w3b) {
  int i = blockIdx.x * 256 + threadIdx.x;     // 24576
  if (i >= 24576) return;
  int j = i & 7, l = (i >> 3) & 63, nt = (i >> 9) & 7, kt = i >> 12;
  int k = kt * 32 + (l >> 4) * 8 + j;
  int c = nt * 16 + (l & 15);
  int kk = k >> 6, e = k & 63;
  float v = (e < 50) ? w3[c * 150 + e * 3 + kk] : 0.f;
  w3b[i] = f2bf(v);
}

// conv4 weights [c=128][ci=128][kk=4] -> frag-linear B: [kt=16][nt=8][lane][j]
__global__ __launch_bounds__(256) void k_repb4(const float* __restrict__ w4,
                                               u16* __restrict__ w4b) {
  int i = blockIdx.x * 256 + threadIdx.x;     // 65536
  int j = i & 7, l = (i >> 3) & 63, nt = (i >> 9) & 7, kt = i >> 12;
  int k = kt * 32 + (l >> 4) * 8 + j;
  int c = nt * 16 + (l & 15);
  int kk = k >> 7, ci = k & 127;
  w4b[i] = f2bf(w4[c * 512 + ci * 4 + kk]);
}

// gru_whh [768][256] -> bf16 frag-linear B for gh GEMM: B[k][n]=whh[n][k]
// idx = ((nt*8+kt)*64 + l)*8 + j ; n = nt*16+(l&15), k = kt*32+(l>>4)*8+j
__global__ __launch_bounds__(256) void k_repwhh(const float* __restrict__ whh,
                                                u16* __restrict__ whhb) {
  int i = blockIdx.x * 256 + threadIdx.x;     // 196608
  int j = i & 7, l = (i >> 3) & 63, kt = (i >> 9) & 7, nt = i >> 12;
  int n = nt * 16 + (l & 15);
  int k = kt * 32 + (l >> 4) * 8 + j;
  whhb[i] = f2bf(whh[n * 256 + k]);
}

// Wcomb[g][c] = gru_wih[g]@mh_w[:,c]; b1[g] = gru_bih[g] + wih[g]@mh_b
// 8 g-rows per block (amortize mh_w traffic 201MB -> 25MB)
__global__ __launch_bounds__(256) void k_pcomb(const float* __restrict__ wih,
                                               const float* __restrict__ mh_w,
                                               const float* __restrict__ mh_b,
                                               const float* __restrict__ bih,
                                               float* __restrict__ Wcomb,
                                               float* __restrict__ b1) {
  int g0 = blockIdx.x * 8, t = threadIdx.x;
  float acc[8] = {0.f, 0.f, 0.f, 0.f, 0.f, 0.f, 0.f, 0.f};
  for (int j = 0; j < 256; ++j) {
    float wv = mh_w[j * 256 + t];
#pragma unroll
    for (int r = 0; r < 8; ++r) acc[r] += wih[(g0 + r) * 256 + j] * wv;
  }
#pragma unroll
  for (int r = 0; r < 8; ++r) Wcomb[(g0 + r) * 256 + t] = acc[r];
  __shared__ float red[4][8];
  float mb = mh_b[t];
#pragma unroll
  for (int r = 0; r < 8; ++r) {
    float v = wih[(g0 + r) * 256 + t] * mb;
    v += __shfl_down(v, 32); v += __shfl_down(v, 16); v += __shfl_down(v, 8);
    v += __shfl_down(v, 4);  v += __shfl_down(v, 2);  v += __shfl_down(v, 1);
    if ((t & 63) == 0) red[t >> 6][r] = v;
  }
  __syncthreads();
  if (t < 8) b1[g0 + t] = bih[g0 + t] + red[0][t] + red[1][t] + red[2][t] + red[3][t];
}

// Fold lags/weather/event/text projections through merge_w.
__global__ __launch_bounds__(256) void k_pmerge(const float* __restrict__ merge_w,
                                                const float* __restrict__ text_w,
                                                const float* __restrict__ lags_w,
                                                const float* __restrict__ weather_w,
                                                const float* __restrict__ event_w,
                                                const float* __restrict__ lags_b,
                                                const float* __restrict__ weather_b,
                                                const float* __restrict__ event_b,
                                                const float* __restrict__ text_b,
                                                float* __restrict__ MtxT,
                                                float* __restrict__ A_l,
                                                float* __restrict__ MwT,
                                                float* __restrict__ MeT,
                                                float* __restrict__ bias_deg) {
  int blk = blockIdx.x, t = threadIdx.x;
  if (blk < 128) {
    int c = blk;
    float acc = 0.f;
    for (int j = 0; j < 256; ++j)
      acc += merge_w[t * 1024 + 768 + j] * text_w[j * 128 + c];
    MtxT[c * 256 + t] = acc;
  } else {
    float a = 0.f, w0 = 0.f, w1 = 0.f, e0 = 0.f, e1 = 0.f, e2 = 0.f, e3 = 0.f, bd = 0.f;
    for (int j = 0; j < 256; ++j) {
      float m0 = merge_w[t * 1024 + j];
      float m1 = merge_w[t * 1024 + 256 + j];
      float m2 = merge_w[t * 1024 + 512 + j];
      float m3 = merge_w[t * 1024 + 768 + j];
      a  += m0 * lags_w[j];
      w0 += m1 * weather_w[j * 2 + 0];
      w1 += m1 * weather_w[j * 2 + 1];
      e0 += m2 * event_w[j * 4 + 0];
      e1 += m2 * event_w[j * 4 + 1];
      e2 += m2 * event_w[j * 4 + 2];
      e3 += m2 * event_w[j * 4 + 3];
      bd += m0 * lags_b[j] + m1 * weather_b[j] + m2 * event_b[j] + m3 * text_b[j];
    }
    A_l[t] = a;
    MwT[t] = w0; MwT[256 + t] = w1;
    MeT[t] = e0; MeT[256 + t] = e1; MeT[512 + t] = e2; MeT[768 + t] = e3;
    bias_deg[t] = bd;
  }
}

// ---------------------------------------------------------------------------
// MFMA textCNN. LDS: sx (6.4KB) aliased with sc3 (13.3KB) -> 13.3KB/wave
// -> 12 blocks/CU (was 8). Barrier between last sx read and first sc3 write.
// ---------------------------------------------------------------------------

#define LOADB(DST, SRC, KT)                                                    \
  _Pragma("unroll") for (int nt = 0; nt < 8; ++nt)                             \
      DST[nt] = *(const short8v*)&SRC[((((KT) * 8 + nt) * 64) + l) * 8];

#define AFRAG3(AF, KT) {                                                       \
    const int kk_ = (KT) >> 1;                                                 \
    const int eb_ = 4 * ((KT) & 1) + g;                                        \
    _Pragma("unroll") for (int mt = 0; mt < 3; ++mt) {                         \
      int pr_ = 16 * mt + lr + kk_;                                            \
      int bb_ = eb_ ^ (pr_ & 7);                                               \
      AF[mt] = *(const short8v*)&sx[pr_ * 64 + bb_ * 8];                       \
    } }

#define AFRAG4(AF, KT) {                                                       \
    const int t4_ = 4 * (KT) + g;                                              \
    const int kk_ = t4_ >> 4;                                                  \
    const int bk_ = t4_ & 15;                                                  \
    _Pragma("unroll") for (int mt = 0; mt < 3; ++mt) {                         \
      int pr_ = 16 * mt + lr + kk_;                                            \
      int bb_ = (bk_ & 8) | ((bk_ ^ pr_) & 7);                                 \
      AF[mt] = *(const short8v*)&sc3[pr_ * 128 + bb_ * 8];                     \
    } }

#define MSTEP(AF, BF)                                                          \
  _Pragma("unroll") for (int nt = 0; nt < 8; ++nt)                             \
    _Pragma("unroll") for (int mt = 0; mt < 3; ++mt)                           \
      acc[mt][nt] = MFMA16(AF[mt], BF[nt], acc[mt][nt], 0, 0, 0);

__global__ __launch_bounds__(64) void k_textcnn(const int* __restrict__ text,
                                                const float* __restrict__ emb,
                                                const u16* __restrict__ w3b,
                                                const float* __restrict__ b3,
                                                const u16* __restrict__ w4b,
                                                const float* __restrict__ b4,
                                                float* __restrict__ mx_g) {
  __shared__ u16 sbuf[52 * 128];      // union: sx (3200 u16) | sc3 (6656 u16)
  u16* sx = sbuf;
  u16* sc3 = sbuf;
  const int n = blockIdx.x;
  const int l = threadIdx.x;          // 0..63
  const int lr = l & 15;
  const int g = l >> 4;

  // ---- stage emb -> sx (bf16, swizzled); cols e>=50 zeroed ----
  int idxv = (l < 50) ? text[n * 50 + l] : 0;
  const int e = l;
#pragma unroll 10
  for (int s = 0; s < 50; ++s) {
    int id = __shfl(idxv, s);
    float v = (e < 50) ? emb[id * 50 + e] : 0.f;
    int bb = (e >> 3) ^ (s & 7);
    sx[s * 64 + bb * 8 + (e & 7)] = f2bf(v);
  }
  __syncthreads();

  const float4v zv = {0.f, 0.f, 0.f, 0.f};
  float4v acc[3][8];
#pragma unroll
  for (int mt = 0; mt < 3; ++mt)
#pragma unroll
    for (int nt = 0; nt < 8; ++nt) acc[mt][nt] = zv;

  float b3v[8];
#pragma unroll
  for (int nt = 0; nt < 8; ++nt) b3v[nt] = b3[nt * 16 + lr];

  // ---- conv3: 6 k-tiles, B double-buffered in regs ----
  {
    short8v bA[8], bB[8], a[3];
    LOADB(bA, w3b, 0);
    for (int kt = 0; kt < 6; kt += 2) {
      LOADB(bB, w3b, kt + 1);
      AFRAG3(a, kt);
      MSTEP(a, bA);
      if (kt + 2 < 6) LOADB(bA, w3b, kt + 2);
      AFRAG3(a, kt + 1);
      MSTEP(a, bB);
    }
  }
  __syncthreads();   // sx reads done before sc3 overwrites (aliased)

  // ---- bias+relu+cvt -> sc3 (swizzled); re-zero acc ----
#pragma unroll
  for (int mt = 0; mt < 3; ++mt)
#pragma unroll
    for (int nt = 0; nt < 8; ++nt) {
#pragma unroll
      for (int r = 0; r < 4; ++r) {
        int p = 16 * mt + 4 * g + r;
        int c = 16 * nt + lr;
        float v = fmaxf(acc[mt][nt][r] + b3v[nt], 0.f);
        int bb = (c >> 3) & 15;
        bb = (bb & 8) | ((bb ^ (p & 7)) & 7);
        sc3[p * 128 + bb * 8 + (c & 7)] = f2bf(v);
      }
      acc[mt][nt] = zv;
    }
  __syncthreads();

  // ---- conv4: 16 k-tiles ----
  {
    short8v bA[8], bB[8], a[3];
    LOADB(bA, w4b, 0);
    for (int kt = 0; kt < 16; kt += 2) {
      LOADB(bB, w4b, kt + 1);
      AFRAG4(a, kt);
      MSTEP(a, bA);
      if (kt + 2 < 16) LOADB(bA, w4b, kt + 2);
      AFRAG4(a, kt + 1);
      MSTEP(a, bB);
    }
  }

  // ---- max over valid p (<45), +bias, relu, store ----
#pragma unroll
  for (int nt = 0; nt < 8; ++nt) {
    float m0 = -1e30f;
#pragma unroll
    for (int mt = 0; mt < 3; ++mt)
#pragma unroll
      for (int r = 0; r < 4; ++r) {
        int p = 16 * mt + 4 * g + r;
        if (p < 45) m0 = fmaxf(m0, acc[mt][nt][r]);
      }
    m0 = fmaxf(m0, __shfl_xor(m0, 16));
    m0 = fmaxf(m0, __shfl_xor(m0, 32));
    int c = 16 * nt + lr;
    float bias = b4[c];
    if (g == 0) mx_g[n * 128 + c] = fmaxf(m0 + bias, 0.f);
  }
}

__device__ inline void preds_of(int i, int& p1, int& p2, int& d) {
  int tt = i % 10;
  int base = i - tt;
  if (tt == 0)      { p1 = base + 9;      p2 = -1;             d = 1; }
  else if (tt == 1) { p1 = base;          p2 = -1;             d = 1; }
  else              { p1 = base + tt - 2; p2 = base + tt - 1;  d = 2; }
}

// graph agg + folded merge -> m_bf[N][256] (bf16, pre-BN, relu'd) + BN sums
__global__ __launch_bounds__(256) void k_merge(const float* __restrict__ mx_g,
                                               const float* __restrict__ lags,
                                               const float* __restrict__ weather,
                                               const float* __restrict__ event,
                                               const float* __restrict__ MtxT,
                                               const float* __restrict__ A_l,
                                               const float* __restrict__ MwT,
                                               const float* __restrict__ MeT,
                                               const float* __restrict__ bias_deg,
                                               const float* __restrict__ merge_b,
                                               u16* __restrict__ m_bf,
                                               float* __restrict__ bnsum,
                                               float* __restrict__ bnsumsq) {
  __shared__ __align__(16) float mxs[16 * 128];
  __shared__ float scal[16 * 8];
  const int tid = threadIdx.x;
  const int row0 = blockIdx.x * 16;
  for (int idx = tid; idx < 2048; idx += 256) {
    int r = idx >> 7, c = idx & 127;
    int p1, p2, d;
    preds_of(row0 + r, p1, p2, d);
    float v = mx_g[p1 * 128 + c];
    if (p2 >= 0) v += mx_g[p2 * 128 + c];
    mxs[r * 128 + c] = v;
  }
  if (tid < 16) {
    int p1, p2, d;
    preds_of(row0 + tid, p1, p2, d);
    float sl = lags[p1];
    float sw0 = weather[p1 * 2], sw1 = weather[p1 * 2 + 1];
    float se0 = event[p1 * 4], se1 = event[p1 * 4 + 1];
    float se2 = event[p1 * 4 + 2], se3 = event[p1 * 4 + 3];
    if (p2 >= 0) {
      sl += lags[p2];
      sw0 += weather[p2 * 2]; sw1 += weather[p2 * 2 + 1];
      se0 += event[p2 * 4];     se1 += event[p2 * 4 + 1];
      se2 += event[p2 * 4 + 2]; se3 += event[p2 * 4 + 3];
    }
    scal[tid * 8 + 0] = sl;
    scal[tid * 8 + 1] = sw0; scal[tid * 8 + 2] = sw1;
    scal[tid * 8 + 3] = se0; scal[tid * 8 + 4] = se1;
    scal[tid * 8 + 5] = se2; scal[tid * 8 + 6] = se3;
    scal[tid * 8 + 7] = (float)d;
  }
  __syncthreads();
  const int t = tid;
  float acc[16];
#pragma unroll
  for (int r = 0; r < 16; ++r) acc[r] = 0.f;
  for (int c4 = 0; c4 < 32; ++c4) {
    const int c = c4 * 4;
    float w0 = MtxT[c * 256 + t];
    float w1 = MtxT[(c + 1) * 256 + t];
    float w2 = MtxT[(c + 2) * 256 + t];
    float w3 = MtxT[(c + 3) * 256 + t];
#pragma unroll
    for (int r = 0; r < 16; ++r) {
      float4 mv = *(const float4*)&mxs[r * 128 + c];
      acc[r] += mv.x * w0 + mv.y * w1 + mv.z * w2 + mv.w * w3;
    }
  }
  float al = A_l[t], mw0 = MwT[t], mw1 = MwT[256 + t];
  float me0 = MeT[t], me1 = MeT[256 + t], me2 = MeT[512 + t], me3 = MeT[768 + t];
  float bd = bias_deg[t], mb = merge_b[t];
  float s1 = 0.f, s2 = 0.f;
#pragma unroll
  for (int r = 0; r < 16; ++r) {
    float mp = acc[r] + scal[r * 8] * al + scal[r * 8 + 1] * mw0 + scal[r * 8 + 2] * mw1
             + scal[r * 8 + 3] * me0 + scal[r * 8 + 4] * me1 + scal[r * 8 + 5] * me2
             + scal[r * 8 + 6] * me3 + scal[r * 8 + 7] * bd + mb;
    float mv = fmaxf(mp, 0.f);
    m_bf[(row0 + r) * 256 + t] = f2bf(mv);
    s1 += mv;
    s2 += mv * mv;
  }
  atomicAdd(&bnsum[t], s1);
  atomicAdd(&bnsumsq[t], s2);
}

__global__ __launch_bounds__(256) void k_bna(const float* __restrict__ bnsum,
                                             const float* __restrict__ bnsumsq,
                                             const float* __restrict__ gamma,
                                             const float* __restrict__ beta,
                                             float* __restrict__ svec,
                                             float* __restrict__ tvec) {
  int c = threadIdx.x;
  float mu = bnsum[c] * (1.f / 10240.f);
  float var = bnsumsq[c] * (1.f / 10240.f) - mu * mu;
  float s = gamma[c] * rsqrtf(var + 1e-5f);
  svec[c] = s;
  tvec[c] = beta[c] - mu * s;
}

// blocks 0..767: wbig_b (bf16 frag-linear, BN scale folded)
// blocks 768..1535: bias_big[g] = b1[g] + tvec@Wcomb[g]
__global__ __launch_bounds__(256) void k_bnbc(const float* __restrict__ Wcomb,
                                              const float* __restrict__ svec,
                                              const float* __restrict__ tvec,
                                              const float* __restrict__ b1,
                                              u16* __restrict__ wbig_b,
                                              float* __restrict__ bias_big) {
  int blk = blockIdx.x, t = threadIdx.x;
  __shared__ float red[4];
  if (blk < 768) {
    int i = blk * 256 + t;
    int j = i & 7, l = (i >> 3) & 63, kt = (i >> 9) & 7, nt = i >> 12;
    int n = nt * 16 + (l & 15);
    int k = kt * 32 + (l >> 4) * 8 + j;
    wbig_b[i] = f2bf(Wcomb[n * 256 + k] * svec[k]);
  } else {
    int gg = blk - 768;
    float part = tvec[t] * Wcomb[gg * 256 + t];
    part += __shfl_down(part, 32); part += __shfl_down(part, 16);
    part += __shfl_down(part, 8);  part += __shfl_down(part, 4);
    part += __shfl_down(part, 2);  part += __shfl_down(part, 1);
    if ((t & 63) == 0) red[t >> 6] = part;
    __syncthreads();
    if (t == 0) bias_big[gg] = b1[gg] + red[0] + red[1] + red[2] + red[3];
  }
}

// gi[N][768] = m @ Wbig^T + bias_big  (bf16 MFMA; BN+mh+Wih folded)
// 640 blocks x 16 rows; wave w owns nt in [w*12, w*12+12)
__global__ __launch_bounds__(256) void k_gi(const u16* __restrict__ m_bf,
                                            const u16* __restrict__ wbig_b,
                                            const float* __restrict__ bias_big,
                                            float* __restrict__ gi) {
  const int t = threadIdx.x;
  const int w = t >> 6, l = t & 63, lr = l & 15, g = l >> 4;
  const int row0 = blockIdx.x * 16;
  short8v a[8];
#pragma unroll
  for (int kt = 0; kt < 8; ++kt)
    a[kt] = *(const short8v*)&m_bf[(row0 + lr) * 256 + kt * 32 + g * 8];
  const float4v zv = {0.f, 0.f, 0.f, 0.f};
  float4v acc[12];
#pragma unroll
  for (int j = 0; j < 12; ++j) acc[j] = zv;
#pragma unroll 2
  for (int kt = 0; kt < 8; ++kt) {
#pragma unroll
    for (int j = 0; j < 12; ++j) {
      int nt = w * 12 + j;
      short8v b = *(const short8v*)&wbig_b[((nt * 8 + kt) * 64 + l) * 8];
      acc[j] = MFMA16(a[kt], b, acc[j], 0, 0, 0);
    }
  }
#pragma unroll
  for (int j = 0; j < 12; ++j) {
    int col = (w * 12 + j) * 16 + lr;
    float bb = bias_big[col];
#pragma unroll
    for (int r = 0; r < 4; ++r)
      gi[(row0 + g * 4 + r) * 768 + col] = acc[j][r] + bb;
  }
}

// ---------------------------------------------------------------------------
// Fused GRU, all 10 steps in one kernel. 64 blocks x 16 rows x 4 waves.
// gh = h@whh^T via MFMA; gate-interleaved nt = gate*16 + w*4 + i so each lane
// holds its (r,z,n) triple in-register. h: bf16 in swizzled LDS (A-operand)
// + f32 in per-lane regs (hp). reg-dot accumulated across steps in regs.
// ---------------------------------------------------------------------------
__global__ __launch_bounds__(256) void k_gru_all(const float* __restrict__ gi,
                                                 const u16* __restrict__ whhb,
                                                 const float* __restrict__ bhh,
                                                 const float* __restrict__ reg_w,
                                                 const float* __restrict__ reg_b,
                                                 float* __restrict__ out) {
  __shared__ u16 hb[16 * 256];
  __shared__ float red[4][16];
  const int t = threadIdx.x;
  const int w = t >> 6, l = t & 63, lr = l & 15, g = l >> 4;
  const int row0 = blockIdx.x * 16;
  for (int i = t; i < 4096; i += 256) hb[i] = 0;
  float hp[4][4];                    // [i][r] : h for (row g*4+r, col (w*4+i)*16+lr)
#pragma unroll
  for (int i = 0; i < 4; ++i)
#pragma unroll
    for (int r = 0; r < 4; ++r) hp[i][r] = 0.f;
  float bh[3][4];
#pragma unroll
  for (int gate = 0; gate < 3; ++gate)
#pragma unroll
    for (int i = 0; i < 4; ++i)
      bh[gate][i] = bhh[gate * 256 + (w * 4 + i) * 16 + lr];
  float racc[4] = {0.f, 0.f, 0.f, 0.f};

  for (int s = 0; s < 10; ++s) {
    __syncthreads();                 // hb (init or prev-step writes) visible
    const float4v zv = {0.f, 0.f, 0.f, 0.f};
    float4v acc[3][4];
#pragma unroll
    for (int gate = 0; gate < 3; ++gate)
#pragma unroll
      for (int i = 0; i < 4; ++i) acc[gate][i] = zv;
#pragma unroll
    for (int kt = 0; kt < 8; ++kt) {
      int kb = kt * 4 + g;
      int bb = kb ^ (lr & 7);
      short8v a = *(const short8v*)&hb[lr * 256 + bb * 8];
#pragma unroll
      for (int gate = 0; gate < 3; ++gate)
#pragma unroll
        for (int i = 0; i < 4; ++i) {
          int nt = gate * 16 + w * 4 + i;
          short8v b = *(const short8v*)&whhb[((nt * 8 + kt) * 64 + l) * 8];
          acc[gate][i] = MFMA16(a, b, acc[gate][i], 0, 0, 0);
        }
    }
    __syncthreads();                 // all hb reads done before overwrite
    float rw[4];
#pragma unroll
    for (int i = 0; i < 4; ++i) rw[i] = reg_w[s * 256 + (w * 4 + i) * 16 + lr];
#pragma unroll
    for (int i = 0; i < 4; ++i) {
      int c = (w * 4 + i) * 16 + lr;
#pragma unroll
      for (int r = 0; r < 4; ++r) {
        int node = (row0 + g * 4 + r) * 10 + s;
        float gir = gi[node * 768 + c];
        float giz = gi[node * 768 + 256 + c];
        float gin = gi[node * 768 + 512 + c];
        float ghr = acc[0][i][r] + bh[0][i];
        float ghz = acc[1][i][r] + bh[1][i];
        float ghn = acc[2][i][r] + bh[2][i];
        float rg = 1.f / (1.f + expf(-(gir + ghr)));
        float zg = 1.f / (1.f + expf(-(giz + ghz)));
        float ng = tanhf(gin + rg * ghn);
        float hn = (1.f - zg) * ng + zg * hp[i][r];
        hp[i][r] = hn;
        racc[r] += hn * rw[i];
        int m = g * 4 + r;
        int bb2 = (c >> 3) ^ (m & 7);
        hb[m * 256 + bb2 * 8 + (c & 7)] = f2bf(hn);
      }
    }
  }
#pragma unroll
  for (int r = 0; r < 4; ++r) {
    float v = racc[r];
    v += __shfl_xor(v, 1); v += __shfl_xor(v, 2);
    v += __shfl_xor(v, 4); v += __shfl_xor(v, 8);
    racc[r] = v;
  }
  if (lr == 0) {
#pragma unroll
    for (int r = 0; r < 4; ++r) red[w][g * 4 + r] = racc[r];
  }
  __syncthreads();
  if (t < 16)
    out[row0 + t] = reg_b[0] + red[0][t] + red[1][t] + red[2][t] + red[3][t];
}

extern "C" void kernel_launch(void* const* d_in, const int* in_sizes, int n_in,
                              void* d_out, int out_size, void* d_ws, size_t ws_size,
                              hipStream_t stream) {
  (void)in_sizes; (void)n_in; (void)out_size; (void)ws_size;
  const float* lags      = (const float*)d_in[0];
  const float* weather   = (const float*)d_in[1];
  const float* event     = (const float*)d_in[2];
  const int*   text      = (const int*)d_in[3];
  const float* emb       = (const float*)d_in[4];
  const float* conv3_w   = (const float*)d_in[5];
  const float* conv3_b   = (const float*)d_in[6];
  const float* conv4_w   = (const float*)d_in[7];
  const float* conv4_b   = (const float*)d_in[8];
  const float* lags_w    = (const float*)d_in[9];
  const float* lags_b    = (const float*)d_in[10];
  const float* weather_w = (const float*)d_in[11];
  const float* weather_b = (const float*)d_in[12];
  const float* event_w   = (const float*)d_in[13];
  const float* event_b   = (const float*)d_in[14];
  const float* text_w    = (const float*)d_in[15];
  const float* text_b    = (const float*)d_in[16];
  const float* merge_w   = (const float*)d_in[17];
  const float* merge_b   = (const float*)d_in[18];
  const float* bn_gamma  = (const float*)d_in[19];
  const float* bn_beta   = (const float*)d_in[20];
  const float* mh_w      = (const float*)d_in[21];
  const float* mh_b      = (const float*)d_in[22];
  const float* gru_wih   = (const float*)d_in[23];
  const float* gru_whh   = (const float*)d_in[24];
  const float* gru_bih   = (const float*)d_in[25];
  const float* gru_bhh   = (const float*)d_in[26];
  const float* reg_w     = (const float*)d_in[27];
  const float* reg_b     = (const float*)d_in[28];
  float* out = (float*)d_out;

  float* p = (float*)d_ws;
  float* bnsum    = p; p += 256;            // zeroed
  float* bnsumsq  = p; p += 256;            // zeroed
  float* mx       = p; p += 10240 * 128;
  u16*   m_bf     = (u16*)p; p += 10240 * 128;   // 10240*256 u16
  float* gi       = p; p += 10240 * 768;
  u16*   w3b      = (u16*)p; p += 12288;    // 24576 u16
  u16*   w4b      = (u16*)p; p += 32768;    // 65536 u16
  u16*   whhb     = (u16*)p; p += 98304;    // 196608 u16
  u16*   wbig_b   = (u16*)p; p += 98304;    // 196608 u16
  float* Wcomb    = p; p += 196608;
  float* MtxT     = p; p += 32768;
  float* A_l      = p; p += 256;
  float* MwT      = p; p += 512;
  float* MeT      = p; p += 1024;
  float* bias_deg = p; p += 256;
  float* b1       = p; p += 768;
  float* bias_big = p; p += 768;
  float* svec     = p; p += 256;
  float* tvec     = p; p += 256;

  k_zero<<<dim3(2), dim3(256), 0, stream>>>(bnsum, 512);
  k_repb3<<<dim3(96), dim3(256), 0, stream>>>(conv3_w, w3b);
  k_repb4<<<dim3(256), dim3(256), 0, stream>>>(conv4_w, w4b);
  k_repwhh<<<dim3(768), dim3(256), 0, stream>>>(gru_whh, whhb);
  k_pcomb<<<dim3(96), dim3(256), 0, stream>>>(gru_wih, mh_w, mh_b, gru_bih, Wcomb, b1);
  k_pmerge<<<dim3(129), dim3(256), 0, stream>>>(merge_w, text_w, lags_w, weather_w, event_w,
                                                lags_b, weather_b, event_b, text_b,
                                                MtxT, A_l, MwT, MeT, bias_deg);
  k_textcnn<<<dim3(10240), dim3(64), 0, stream>>>(text, emb, w3b, conv3_b, w4b, conv4_b, mx);
  k_merge<<<dim3(640), dim3(256), 0, stream>>>(mx, lags, weather, event, MtxT, A_l, MwT, MeT,
                                               bias_deg, merge_b, m_bf, bnsum, bnsumsq);
  k_bna<<<dim3(1), dim3(256), 0, stream>>>(bnsum, bnsumsq, bn_gamma, bn_beta, svec, tvec);
  k_bnbc<<<dim3(1536), dim3(256), 0, stream>>>(Wcomb, svec, tvec, b1, wbig_b, bias_big);
  k_gi<<<dim3(640), dim3(256), 0, stream>>>(m_bf, wbig_b, bias_big, gi);
  k_gru_all<<<dim3(64), dim3(256), 0, stream>>>(gi, whhb, gru_bhh, reg_w, reg_b, out);
}

// Round 11
// 618.834 us; speedup vs baseline: 1.0828x; 1.0828x over previous
//
#include <hip/hip_runtime.h>
#include <math.h>

// ---------------------------------------------------------------------------
// Model dims: BS=1024 T=10 H=256 C=128 E=50 SEQ=50 V=50000 NREG=1
// R10 = BISECTION STEP 1: proven-good R2/R9 base + ONLY the 2-wave textcnn.
//   (R4 bundled 3 changes and killed containers 3/3; R2 base ran 3/3.
//    GRU-512 and k_tr/pmerge changes quarantined for later rounds.)
//   Occupancy evidence: 22.7% @19.9KB LDS == 22.6% @13.3KB -> not LDS-capped;
//   consistent with ~8 WG-slots/CU for 1-wave WGs. 2 waves/WG doubles the cap
//   and halves the per-wave latency chain.
// ---------------------------------------------------------------------------

typedef unsigned short u16;
typedef __attribute__((ext_vector_type(8))) short short8v;   // 8 bf16 = 4 VGPR
typedef __attribute__((ext_vector_type(4))) float float4v;
#define MFMA16 __builtin_amdgcn_mfma_f32_16x16x32_bf16

__device__ inline u16 f2bf(float f) {
  unsigned u = __float_as_uint(f);
  u += 0x7FFFu + ((u >> 16) & 1u);            // RNE
  return (u16)(u >> 16);
}

__global__ __launch_bounds__(256) void k_zero(float* __restrict__ p, int n) {
  int i = blockIdx.x * 256 + threadIdx.x;
  if (i < n) p[i] = 0.f;
}

// conv3 weights [c=128][e=50][kk=3] -> frag-linear B: [kt=6][nt=8][lane=64][j=8]
__global__ __launch_bounds__(256) void k_repb3(const float* __restrict__ w3,
                                               u16* __restrict__ w3b) {
  int i = blockIdx.x * 256 + threadIdx.x;     // 24576
  if (i >= 24576) return;
  int j = i & 7, l = (i >> 3) & 63, nt = (i >> 9) & 7, kt = i >> 12;
  int k = kt * 32 + (l >> 4) * 8 + j;
  int c = nt * 16 + (l & 15);
  int kk = k >> 6, e = k & 63;
  float v = (e < 50) ? w3[c * 150 + e * 3 + kk] : 0.f;
  w3b[i] = f2bf(v);
}

// conv4 weights [c=128][ci=128][kk=4] -> frag-linear B: [kt=16][nt=8][lane][j]
__global__ __launch_bounds__(256) void k_repb4(const float* __restrict__ w4,
                                               u16* __restrict__ w4b) {
  int i = blockIdx.x * 256 + threadIdx.x;     // 65536
  int j = i & 7, l = (i >> 3) & 63, nt = (i >> 9) & 7, kt = i >> 12;
  int k = kt * 32 + (l >> 4) * 8 + j;
  int c = nt * 16 + (l & 15);
  int kk = k >> 7, ci = k & 127;
  w4b[i] = f2bf(w4[c * 512 + ci * 4 + kk]);
}

// gru_whh [768][256] -> bf16 frag-linear B for gh GEMM: B[k][n]=whh[n][k]
__global__ __launch_bounds__(256) void k_repwhh(const float* __restrict__ whh,
                                                u16* __restrict__ whhb) {
  int i = blockIdx.x * 256 + threadIdx.x;     // 196608
  int j = i & 7, l = (i >> 3) & 63, kt = (i >> 9) & 7, nt = i >> 12;
  int n = nt * 16 + (l & 15);
  int k = kt * 32 + (l >> 4) * 8 + j;
  whhb[i] = f2bf(whh[n * 256 + k]);
}

// Wcomb[g][c] = gru_wih[g]@mh_w[:,c]; b1[g] = gru_bih[g] + wih[g]@mh_b
__global__ __launch_bounds__(256) void k_pcomb(const float* __restrict__ wih,
                                               const float* __restrict__ mh_w,
                                               const float* __restrict__ mh_b,
                                               const float* __restrict__ bih,
                                               float* __restrict__ Wcomb,
                                               float* __restrict__ b1) {
  int g0 = blockIdx.x * 8, t = threadIdx.x;
  float acc[8] = {0.f, 0.f, 0.f, 0.f, 0.f, 0.f, 0.f, 0.f};
  for (int j = 0; j < 256; ++j) {
    float wv = mh_w[j * 256 + t];
#pragma unroll
    for (int r = 0; r < 8; ++r) acc[r] += wih[(g0 + r) * 256 + j] * wv;
  }
#pragma unroll
  for (int r = 0; r < 8; ++r) Wcomb[(g0 + r) * 256 + t] = acc[r];
  __shared__ float red[4][8];
  float mb = mh_b[t];
#pragma unroll
  for (int r = 0; r < 8; ++r) {
    float v = wih[(g0 + r) * 256 + t] * mb;
    v += __shfl_down(v, 32); v += __shfl_down(v, 16); v += __shfl_down(v, 8);
    v += __shfl_down(v, 4);  v += __shfl_down(v, 2);  v += __shfl_down(v, 1);
    if ((t & 63) == 0) red[t >> 6][r] = v;
  }
  __syncthreads();
  if (t < 8) b1[g0 + t] = bih[g0 + t] + red[0][t] + red[1][t] + red[2][t] + red[3][t];
}

// Fold lags/weather/event/text projections through merge_w.
__global__ __launch_bounds__(256) void k_pmerge(const float* __restrict__ merge_w,
                                                const float* __restrict__ text_w,
                                                const float* __restrict__ lags_w,
                                                const float* __restrict__ weather_w,
                                                const float* __restrict__ event_w,
                                                const float* __restrict__ lags_b,
                                                const float* __restrict__ weather_b,
                                                const float* __restrict__ event_b,
                                                const float* __restrict__ text_b,
                                                float* __restrict__ MtxT,
                                                float* __restrict__ A_l,
                                                float* __restrict__ MwT,
                                                float* __restrict__ MeT,
                                                float* __restrict__ bias_deg) {
  int blk = blockIdx.x, t = threadIdx.x;
  if (blk < 128) {
    int c = blk;
    float acc = 0.f;
    for (int j = 0; j < 256; ++j)
      acc += merge_w[t * 1024 + 768 + j] * text_w[j * 128 + c];
    MtxT[c * 256 + t] = acc;
  } else {
    float a = 0.f, w0 = 0.f, w1 = 0.f, e0 = 0.f, e1 = 0.f, e2 = 0.f, e3 = 0.f, bd = 0.f;
    for (int j = 0; j < 256; ++j) {
      float m0 = merge_w[t * 1024 + j];
      float m1 = merge_w[t * 1024 + 256 + j];
      float m2 = merge_w[t * 1024 + 512 + j];
      float m3 = merge_w[t * 1024 + 768 + j];
      a  += m0 * lags_w[j];
      w0 += m1 * weather_w[j * 2 + 0];
      w1 += m1 * weather_w[j * 2 + 1];
      e0 += m2 * event_w[j * 4 + 0];
      e1 += m2 * event_w[j * 4 + 1];
      e2 += m2 * event_w[j * 4 + 2];
      e3 += m2 * event_w[j * 4 + 3];
      bd += m0 * lags_b[j] + m1 * weather_b[j] + m2 * event_b[j] + m3 * text_b[j];
    }
    A_l[t] = a;
    MwT[t] = w0; MwT[256 + t] = w1;
    MeT[t] = e0; MeT[256 + t] = e1; MeT[512 + t] = e2; MeT[768 + t] = e3;
    bias_deg[t] = bd;
  }
}

// ---------------------------------------------------------------------------
// MFMA textCNN: 2 waves/block, one node/block. Wave w owns channels
// c in [64w, 64w+64) (4 n-tiles). sx/sc3 shared (aliased union, 13.3KB).
// ---------------------------------------------------------------------------

#define LOADB4(DST, SRC, KT)                                                   \
  _Pragma("unroll") for (int q = 0; q < 4; ++q)                                \
      DST[q] = *(const short8v*)&SRC[((((KT) * 8 + NB + q) * 64) + l) * 8];

#define AFRAG3(AF, KT) {                                                       \
    const int kk_ = (KT) >> 1;                                                 \
    const int eb_ = 4 * ((KT) & 1) + g;                                        \
    _Pragma("unroll") for (int mt = 0; mt < 3; ++mt) {                         \
      int pr_ = 16 * mt + lr + kk_;                                            \
      int bb_ = eb_ ^ (pr_ & 7);                                               \
      AF[mt] = *(const short8v*)&sx[pr_ * 64 + bb_ * 8];                       \
    } }

#define AFRAG4(AF, KT) {                                                       \
    const int t4_ = 4 * (KT) + g;                                              \
    const int kk_ = t4_ >> 4;                                                  \
    const int bk_ = t4_ & 15;                                                  \
    _Pragma("unroll") for (int mt = 0; mt < 3; ++mt) {                         \
      int pr_ = 16 * mt + lr + kk_;                                            \
      int bb_ = (bk_ & 8) | ((bk_ ^ pr_) & 7);                                 \
      AF[mt] = *(const short8v*)&sc3[pr_ * 128 + bb_ * 8];                     \
    } }

#define MSTEP4(AF, BF)                                                         \
  _Pragma("unroll") for (int q = 0; q < 4; ++q)                                \
    _Pragma("unroll") for (int mt = 0; mt < 3; ++mt)                           \
      acc[mt][q] = MFMA16(AF[mt], BF[q], acc[mt][q], 0, 0, 0);

__global__ __launch_bounds__(128) void k_textcnn(const int* __restrict__ text,
                                                 const float* __restrict__ emb,
                                                 const u16* __restrict__ w3b,
                                                 const float* __restrict__ b3,
                                                 const u16* __restrict__ w4b,
                                                 const float* __restrict__ b4,
                                                 float* __restrict__ mx_g) {
  __shared__ u16 sbuf[52 * 128];      // union: sx (3200 u16) | sc3 (6656 u16)
  u16* sx = sbuf;
  u16* sc3 = sbuf;
  const int n = blockIdx.x;
  const int t = threadIdx.x;          // 0..127
  const int wv = t >> 6;              // wave 0/1
  const int l = t & 63;
  const int lr = l & 15;
  const int g = l >> 4;
  const int NB = wv * 4;              // n-tile base

  // ---- stage emb -> sx (bf16, swizzled); wave wv stages s in [25wv,25wv+25) ----
  int idxv = (l < 25) ? text[n * 50 + wv * 25 + l] : 0;
  const int e = l;
#pragma unroll 5
  for (int si = 0; si < 25; ++si) {
    int s = wv * 25 + si;
    int id = __shfl(idxv, si);
    float v = (e < 50) ? emb[id * 50 + e] : 0.f;
    int bb = (e >> 3) ^ (s & 7);
    sx[s * 64 + bb * 8 + (e & 7)] = f2bf(v);
  }
  __syncthreads();

  const float4v zv = {0.f, 0.f, 0.f, 0.f};
  float4v acc[3][4];
#pragma unroll
  for (int mt = 0; mt < 3; ++mt)
#pragma unroll
    for (int q = 0; q < 4; ++q) acc[mt][q] = zv;

  float b3v[4];
#pragma unroll
  for (int q = 0; q < 4; ++q) b3v[q] = b3[(NB + q) * 16 + lr];

  // ---- conv3: 6 k-tiles, B double-buffered in regs ----
  {
    short8v bA[4], bB[4], a[3];
    LOADB4(bA, w3b, 0);
    for (int kt = 0; kt < 6; kt += 2) {
      LOADB4(bB, w3b, kt + 1);
      AFRAG3(a, kt);
      MSTEP4(a, bA);
      if (kt + 2 < 6) LOADB4(bA, w3b, kt + 2);
      AFRAG3(a, kt + 1);
      MSTEP4(a, bB);
    }
  }
  __syncthreads();   // both waves' sx reads done before sc3 overwrites (aliased)

  // ---- bias+relu+cvt -> sc3 (swizzled); re-zero acc ----
#pragma unroll
  for (int mt = 0; mt < 3; ++mt)
#pragma unroll
    for (int q = 0; q < 4; ++q) {
#pragma unroll
      for (int r = 0; r < 4; ++r) {
        int p = 16 * mt + 4 * g + r;
        int c = (NB + q) * 16 + lr;
        float v = fmaxf(acc[mt][q][r] + b3v[q], 0.f);
        int bb = (c >> 3) & 15;
        bb = (bb & 8) | ((bb ^ (p & 7)) & 7);
        sc3[p * 128 + bb * 8 + (c & 7)] = f2bf(v);
      }
      acc[mt][q] = zv;
    }
  __syncthreads();

  // ---- conv4: 16 k-tiles ----
  {
    short8v bA[4], bB[4], a[3];
    LOADB4(bA, w4b, 0);
    for (int kt = 0; kt < 16; kt += 2) {
      LOADB4(bB, w4b, kt + 1);
      AFRAG4(a, kt);
      MSTEP4(a, bA);
      if (kt + 2 < 16) LOADB4(bA, w4b, kt + 2);
      AFRAG4(a, kt + 1);
      MSTEP4(a, bB);
    }
  }

  // ---- max over valid p (<45), +bias, relu, store ----
#pragma unroll
  for (int q = 0; q < 4; ++q) {
    float m0 = -1e30f;
#pragma unroll
    for (int mt = 0; mt < 3; ++mt)
#pragma unroll
      for (int r = 0; r < 4; ++r) {
        int p = 16 * mt + 4 * g + r;
        if (p < 45) m0 = fmaxf(m0, acc[mt][q][r]);
      }
    m0 = fmaxf(m0, __shfl_xor(m0, 16));
    m0 = fmaxf(m0, __shfl_xor(m0, 32));
    int c = (NB + q) * 16 + lr;
    float bias = b4[c];
    if (g == 0) mx_g[n * 128 + c] = fmaxf(m0 + bias, 0.f);
  }
}

__device__ inline void preds_of(int i, int& p1, int& p2, int& d) {
  int tt = i % 10;
  int base = i - tt;
  if (tt == 0)      { p1 = base + 9;      p2 = -1;             d = 1; }
  else if (tt == 1) { p1 = base;          p2 = -1;             d = 1; }
  else              { p1 = base + tt - 2; p2 = base + tt - 1;  d = 2; }
}

// graph agg + folded merge -> m_bf[N][256] (bf16, pre-BN, relu'd) + BN sums
__global__ __launch_bounds__(256) void k_merge(const float* __restrict__ mx_g,
                                               const float* __restrict__ lags,
                                               const float* __restrict__ weather,
                                               const float* __restrict__ event,
                                               const float* __restrict__ MtxT,
                                               const float* __restrict__ A_l,
                                               const float* __restrict__ MwT,
                                               const float* __restrict__ MeT,
                                               const float* __restrict__ bias_deg,
                                               const float* __restrict__ merge_b,
                                               u16* __restrict__ m_bf,
                                               float* __restrict__ bnsum,
                                               float* __restrict__ bnsumsq) {
  __shared__ __align__(16) float mxs[16 * 128];
  __shared__ float scal[16 * 8];
  const int tid = threadIdx.x;
  const int row0 = blockIdx.x * 16;
  for (int idx = tid; idx < 2048; idx += 256) {
    int r = idx >> 7, c = idx & 127;
    int p1, p2, d;
    preds_of(row0 + r, p1, p2, d);
    float v = mx_g[p1 * 128 + c];
    if (p2 >= 0) v += mx_g[p2 * 128 + c];
    mxs[r * 128 + c] = v;
  }
  if (tid < 16) {
    int p1, p2, d;
    preds_of(row0 + tid, p1, p2, d);
    float sl = lags[p1];
    float sw0 = weather[p1 * 2], sw1 = weather[p1 * 2 + 1];
    float se0 = event[p1 * 4], se1 = event[p1 * 4 + 1];
    float se2 = event[p1 * 4 + 2], se3 = event[p1 * 4 + 3];
    if (p2 >= 0) {
      sl += lags[p2];
      sw0 += weather[p2 * 2]; sw1 += weather[p2 * 2 + 1];
      se0 += event[p2 * 4];     se1 += event[p2 * 4 + 1];
      se2 += event[p2 * 4 + 2]; se3 += event[p2 * 4 + 3];
    }
    scal[tid * 8 + 0] = sl;
    scal[tid * 8 + 1] = sw0; scal[tid * 8 + 2] = sw1;
    scal[tid * 8 + 3] = se0; scal[tid * 8 + 4] = se1;
    scal[tid * 8 + 5] = se2; scal[tid * 8 + 6] = se3;
    scal[tid * 8 + 7] = (float)d;
  }
  __syncthreads();
  const int t = tid;
  float acc[16];
#pragma unroll
  for (int r = 0; r < 16; ++r) acc[r] = 0.f;
  for (int c4 = 0; c4 < 32; ++c4) {
    const int c = c4 * 4;
    float w0 = MtxT[c * 256 + t];
    float w1 = MtxT[(c + 1) * 256 + t];
    float w2 = MtxT[(c + 2) * 256 + t];
    float w3 = MtxT[(c + 3) * 256 + t];
#pragma unroll
    for (int r = 0; r < 16; ++r) {
      float4 mv = *(const float4*)&mxs[r * 128 + c];
      acc[r] += mv.x * w0 + mv.y * w1 + mv.z * w2 + mv.w * w3;
    }
  }
  float al = A_l[t], mw0 = MwT[t], mw1 = MwT[256 + t];
  float me0 = MeT[t], me1 = MeT[256 + t], me2 = MeT[512 + t], me3 = MeT[768 + t];
  float bd = bias_deg[t], mb = merge_b[t];
  float s1 = 0.f, s2 = 0.f;
#pragma unroll
  for (int r = 0; r < 16; ++r) {
    float mp = acc[r] + scal[r * 8] * al + scal[r * 8 + 1] * mw0 + scal[r * 8 + 2] * mw1
             + scal[r * 8 + 3] * me0 + scal[r * 8 + 4] * me1 + scal[r * 8 + 5] * me2
             + scal[r * 8 + 6] * me3 + scal[r * 8 + 7] * bd + mb;
    float mv = fmaxf(mp, 0.f);
    m_bf[(row0 + r) * 256 + t] = f2bf(mv);
    s1 += mv;
    s2 += mv * mv;
  }
  atomicAdd(&bnsum[t], s1);
  atomicAdd(&bnsumsq[t], s2);
}

__global__ __launch_bounds__(256) void k_bna(const float* __restrict__ bnsum,
                                             const float* __restrict__ bnsumsq,
                                             const float* __restrict__ gamma,
                                             const float* __restrict__ beta,
                                             float* __restrict__ svec,
                                             float* __restrict__ tvec) {
  int c = threadIdx.x;
  float mu = bnsum[c] * (1.f / 10240.f);
  float var = bnsumsq[c] * (1.f / 10240.f) - mu * mu;
  float s = gamma[c] * rsqrtf(var + 1e-5f);
  svec[c] = s;
  tvec[c] = beta[c] - mu * s;
}

// blocks 0..767: wbig_b (bf16 frag-linear, BN scale folded)
// blocks 768..1535: bias_big[g] = b1[g] + tvec@Wcomb[g]
__global__ __launch_bounds__(256) void k_bnbc(const float* __restrict__ Wcomb,
                                              const float* __restrict__ svec,
                                              const float* __restrict__ tvec,
                                              const float* __restrict__ b1,
                                              u16* __restrict__ wbig_b,
                                              float* __restrict__ bias_big) {
  int blk = blockIdx.x, t = threadIdx.x;
  __shared__ float red[4];
  if (blk < 768) {
    int i = blk * 256 + t;
    int j = i & 7, l = (i >> 3) & 63, kt = (i >> 9) & 7, nt = i >> 12;
    int n = nt * 16 + (l & 15);
    int k = kt * 32 + (l >> 4) * 8 + j;
    wbig_b[i] = f2bf(Wcomb[n * 256 + k] * svec[k]);
  } else {
    int gg = blk - 768;
    float part = tvec[t] * Wcomb[gg * 256 + t];
    part += __shfl_down(part, 32); part += __shfl_down(part, 16);
    part += __shfl_down(part, 8);  part += __shfl_down(part, 4);
    part += __shfl_down(part, 2);  part += __shfl_down(part, 1);
    if ((t & 63) == 0) red[t >> 6] = part;
    __syncthreads();
    if (t == 0) bias_big[gg] = b1[gg] + red[0] + red[1] + red[2] + red[3];
  }
}

// gi[N][768] = m @ Wbig^T + bias_big  (bf16 MFMA; BN+mh+Wih folded)
// 640 blocks x 16 rows; wave w owns nt in [w*12, w*12+12)
__global__ __launch_bounds__(256) void k_gi(const u16* __restrict__ m_bf,
                                            const u16* __restrict__ wbig_b,
                                            const float* __restrict__ bias_big,
                                            float* __restrict__ gi) {
  const int t = threadIdx.x;
  const int w = t >> 6, l = t & 63, lr = l & 15, g = l >> 4;
  const int row0 = blockIdx.x * 16;
  short8v a[8];
#pragma unroll
  for (int kt = 0; kt < 8; ++kt)
    a[kt] = *(const short8v*)&m_bf[(row0 + lr) * 256 + kt * 32 + g * 8];
  const float4v zv = {0.f, 0.f, 0.f, 0.f};
  float4v acc[12];
#pragma unroll
  for (int j = 0; j < 12; ++j) acc[j] = zv;
#pragma unroll 2
  for (int kt = 0; kt < 8; ++kt) {
#pragma unroll
    for (int j = 0; j < 12; ++j) {
      int nt = w * 12 + j;
      short8v b = *(const short8v*)&wbig_b[((nt * 8 + kt) * 64 + l) * 8];
      acc[j] = MFMA16(a[kt], b, acc[j], 0, 0, 0);
    }
  }
#pragma unroll
  for (int j = 0; j < 12; ++j) {
    int col = (w * 12 + j) * 16 + lr;
    float bb = bias_big[col];
#pragma unroll
    for (int r = 0; r < 4; ++r)
      gi[(row0 + g * 4 + r) * 768 + col] = acc[j][r] + bb;
  }
}

// ---------------------------------------------------------------------------
// Fused GRU, all 10 steps in one kernel. 64 blocks x 16 rows x 4 waves.
// (R2 version — kept unchanged for bisection.)
// ---------------------------------------------------------------------------
__global__ __launch_bounds__(256) void k_gru_all(const float* __restrict__ gi,
                                                 const u16* __restrict__ whhb,
                                                 const float* __restrict__ bhh,
                                                 const float* __restrict__ reg_w,
                                                 const float* __restrict__ reg_b,
                                                 float* __restrict__ out) {
  __shared__ u16 hb[16 * 256];
  __shared__ float red[4][16];
  const int t = threadIdx.x;
  const int w = t >> 6, l = t & 63, lr = l & 15, g = l >> 4;
  const int row0 = blockIdx.x * 16;
  for (int i = t; i < 4096; i += 256) hb[i] = 0;
  float hp[4][4];                    // [i][r] : h for (row g*4+r, col (w*4+i)*16+lr)
#pragma unroll
  for (int i = 0; i < 4; ++i)
#pragma unroll
    for (int r = 0; r < 4; ++r) hp[i][r] = 0.f;
  float bh[3][4];
#pragma unroll
  for (int gate = 0; gate < 3; ++gate)
#pragma unroll
    for (int i = 0; i < 4; ++i)
      bh[gate][i] = bhh[gate * 256 + (w * 4 + i) * 16 + lr];
  float racc[4] = {0.f, 0.f, 0.f, 0.f};

  for (int s = 0; s < 10; ++s) {
    __syncthreads();                 // hb (init or prev-step writes) visible
    const float4v zv = {0.f, 0.f, 0.f, 0.f};
    float4v acc[3][4];
#pragma unroll
    for (int gate = 0; gate < 3; ++gate)
#pragma unroll
      for (int i = 0; i < 4; ++i) acc[gate][i] = zv;
#pragma unroll
    for (int kt = 0; kt < 8; ++kt) {
      int kb = kt * 4 + g;
      int bb = kb ^ (lr & 7);
      short8v a = *(const short8v*)&hb[lr * 256 + bb * 8];
#pragma unroll
      for (int gate = 0; gate < 3; ++gate)
#pragma unroll
        for (int i = 0; i < 4; ++i) {
          int nt = gate * 16 + w * 4 + i;
          short8v b = *(const short8v*)&whhb[((nt * 8 + kt) * 64 + l) * 8];
          acc[gate][i] = MFMA16(a, b, acc[gate][i], 0, 0, 0);
        }
    }
    __syncthreads();                 // all hb reads done before overwrite
    float rw[4];
#pragma unroll
    for (int i = 0; i < 4; ++i) rw[i] = reg_w[s * 256 + (w * 4 + i) * 16 + lr];
#pragma unroll
    for (int i = 0; i < 4; ++i) {
      int c = (w * 4 + i) * 16 + lr;
#pragma unroll
      for (int r = 0; r < 4; ++r) {
        int node = (row0 + g * 4 + r) * 10 + s;
        float gir = gi[node * 768 + c];
        float giz = gi[node * 768 + 256 + c];
        float gin = gi[node * 768 + 512 + c];
        float ghr = acc[0][i][r] + bh[0][i];
        float ghz = acc[1][i][r] + bh[1][i];
        float ghn = acc[2][i][r] + bh[2][i];
        float rg = 1.f / (1.f + expf(-(gir + ghr)));
        float zg = 1.f / (1.f + expf(-(giz + ghz)));
        float ng = tanhf(gin + rg * ghn);
        float hn = (1.f - zg) * ng + zg * hp[i][r];
        hp[i][r] = hn;
        racc[r] += hn * rw[i];
        int m = g * 4 + r;
        int bb2 = (c >> 3) ^ (m & 7);
        hb[m * 256 + bb2 * 8 + (c & 7)] = f2bf(hn);
      }
    }
  }
#pragma unroll
  for (int r = 0; r < 4; ++r) {
    float v = racc[r];
    v += __shfl_xor(v, 1); v += __shfl_xor(v, 2);
    v += __shfl_xor(v, 4); v += __shfl_xor(v, 8);
    racc[r] = v;
  }
  if (lr == 0) {
#pragma unroll
    for (int r = 0; r < 4; ++r) red[w][g * 4 + r] = racc[r];
  }
  __syncthreads();
  if (t < 16)
    out[row0 + t] = reg_b[0] + red[0][t] + red[1][t] + red[2][t] + red[3][t];
}

extern "C" void kernel_launch(void* const* d_in, const int* in_sizes, int n_in,
                              void* d_out, int out_size, void* d_ws, size_t ws_size,
                              hipStream_t stream) {
  (void)in_sizes; (void)n_in; (void)out_size; (void)ws_size;
  const float* lags      = (const float*)d_in[0];
  const float* weather   = (const float*)d_in[1];
  const float* event     = (const float*)d_in[2];
  const int*   text      = (const int*)d_in[3];
  const float* emb       = (const float*)d_in[4];
  const float* conv3_w   = (const float*)d_in[5];
  const float* conv3_b   = (const float*)d_in[6];
  const float* conv4_w   = (const float*)d_in[7];
  const float* conv4_b   = (const float*)d_in[8];
  const float* lags_w    = (const float*)d_in[9];
  const float* lags_b    = (const float*)d_in[10];
  const float* weather_w = (const float*)d_in[11];
  const float* weather_b = (const float*)d_in[12];
  const float* event_w   = (const float*)d_in[13];
  const float* event_b   = (const float*)d_in[14];
  const float* text_w    = (const float*)d_in[15];
  const float* text_b    = (const float*)d_in[16];
  const float* merge_w   = (const float*)d_in[17];
  const float* merge_b   = (const float*)d_in[18];
  const float* bn_gamma  = (const float*)d_in[19];
  const float* bn_beta   = (const float*)d_in[20];
  const float* mh_w      = (const float*)d_in[21];
  const float* mh_b      = (const float*)d_in[22];
  const float* gru_wih   = (const float*)d_in[23];
  const float* gru_whh   = (const float*)d_in[24];
  const float* gru_bih   = (const float*)d_in[25];
  const float* gru_bhh   = (const float*)d_in[26];
  const float* reg_w     = (const float*)d_in[27];
  const float* reg_b     = (const float*)d_in[28];
  float* out = (float*)d_out;

  float* p = (float*)d_ws;
  float* bnsum    = p; p += 256;            // zeroed
  float* bnsumsq  = p; p += 256;            // zeroed
  float* mx       = p; p += 10240 * 128;
  u16*   m_bf     = (u16*)p; p += 10240 * 128;   // 10240*256 u16
  float* gi       = p; p += 10240 * 768;
  u16*   w3b      = (u16*)p; p += 12288;    // 24576 u16
  u16*   w4b      = (u16*)p; p += 32768;    // 65536 u16
  u16*   whhb     = (u16*)p; p += 98304;    // 196608 u16
  u16*   wbig_b   = (u16*)p; p += 98304;    // 196608 u16
  float* Wcomb    = p; p += 196608;
  float* MtxT     = p; p += 32768;
  float* A_l      = p; p += 256;
  float* MwT      = p; p += 512;
  float* MeT      = p; p += 1024;
  float* bias_deg = p; p += 256;
  float* b1       = p; p += 768;
  float* bias_big = p; p += 768;
  float* svec     = p; p += 256;
  float* tvec     = p; p += 256;

  k_zero<<<dim3(2), dim3(256), 0, stream>>>(bnsum, 512);
  k_repb3<<<dim3(96), dim3(256), 0, stream>>>(conv3_w, w3b);
  k_repb4<<<dim3(256), dim3(256), 0, stream>>>(conv4_w, w4b);
  k_repwhh<<<dim3(768), dim3(256), 0, stream>>>(gru_whh, whhb);
  k_pcomb<<<dim3(96), dim3(256), 0, stream>>>(gru_wih, mh_w, mh_b, gru_bih, Wcomb, b1);
  k_pmerge<<<dim3(129), dim3(256), 0, stream>>>(merge_w, text_w, lags_w, weather_w, event_w,
                                                lags_b, weather_b, event_b, text_b,
                                                MtxT, A_l, MwT, MeT, bias_deg);
  k_textcnn<<<dim3(10240), dim3(128), 0, stream>>>(text, emb, w3b, conv3_b, w4b, conv4_b, mx);
  k_merge<<<dim3(640), dim3(256), 0, stream>>>(mx, lags, weather, event, MtxT, A_l, MwT, MeT,
                                               bias_deg, merge_b, m_bf, bnsum, bnsumsq);
  k_bna<<<dim3(1), dim3(256), 0, stream>>>(bnsum, bnsumsq, bn_gamma, bn_beta, svec, tvec);
  k_bnbc<<<dim3(1536), dim3(256), 0, stream>>>(Wcomb, svec, tvec, b1, wbig_b, bias_big);
  k_gi<<<dim3(640), dim3(256), 0, stream>>>(m_bf, wbig_b, bias_big, gi);
  k_gru_all<<<dim3(64), dim3(256), 0, stream>>>(gi, whhb, gru_bhh, reg_w, reg_b, out);
}

// Round 12
// 564.638 us; speedup vs baseline: 1.1867x; 1.0960x over previous
//
#include <hip/hip_runtime.h>
#include <math.h>

// ---------------------------------------------------------------------------
// Model dims: BS=1024 T=10 H=256 C=128 E=50 SEQ=50 V=50000 NREG=1
// R11 = BISECTION STEP 2: R10 (proven: 619us, textcnn-2wave OK) + ONLY the
//   8-wave GRU (R4's k_gru_all, 512 thr). If container dies -> GRU-8 is the
//   killer; if runs -> k_tr/pmerge is the last suspect (or infra flake).
//   GRU at 4 waves = 1 wave/SIMD on 64 CUs (latency-starved, same signature
//   textcnn had); 8 waves doubles TLP.
// ---------------------------------------------------------------------------

typedef unsigned short u16;
typedef __attribute__((ext_vector_type(8))) short short8v;   // 8 bf16 = 4 VGPR
typedef __attribute__((ext_vector_type(4))) float float4v;
#define MFMA16 __builtin_amdgcn_mfma_f32_16x16x32_bf16

__device__ inline u16 f2bf(float f) {
  unsigned u = __float_as_uint(f);
  u += 0x7FFFu + ((u >> 16) & 1u);            // RNE
  return (u16)(u >> 16);
}

__global__ __launch_bounds__(256) void k_zero(float* __restrict__ p, int n) {
  int i = blockIdx.x * 256 + threadIdx.x;
  if (i < n) p[i] = 0.f;
}

// conv3 weights [c=128][e=50][kk=3] -> frag-linear B: [kt=6][nt=8][lane=64][j=8]
__global__ __launch_bounds__(256) void k_repb3(const float* __restrict__ w3,
                                               u16* __restrict__ w3b) {
  int i = blockIdx.x * 256 + threadIdx.x;     // 24576
  if (i >= 24576) return;
  int j = i & 7, l = (i >> 3) & 63, nt = (i >> 9) & 7, kt = i >> 12;
  int k = kt * 32 + (l >> 4) * 8 + j;
  int c = nt * 16 + (l & 15);
  int kk = k >> 6, e = k & 63;
  float v = (e < 50) ? w3[c * 150 + e * 3 + kk] : 0.f;
  w3b[i] = f2bf(v);
}

// conv4 weights [c=128][ci=128][kk=4] -> frag-linear B: [kt=16][nt=8][lane][j]
__global__ __launch_bounds__(256) void k_repb4(const float* __restrict__ w4,
                                               u16* __restrict__ w4b) {
  int i = blockIdx.x * 256 + threadIdx.x;     // 65536
  int j = i & 7, l = (i >> 3) & 63, nt = (i >> 9) & 7, kt = i >> 12;
  int k = kt * 32 + (l >> 4) * 8 + j;
  int c = nt * 16 + (l & 15);
  int kk = k >> 7, ci = k & 127;
  w4b[i] = f2bf(w4[c * 512 + ci * 4 + kk]);
}

// gru_whh [768][256] -> bf16 frag-linear B for gh GEMM: B[k][n]=whh[n][k]
__global__ __launch_bounds__(256) void k_repwhh(const float* __restrict__ whh,
                                                u16* __restrict__ whhb) {
  int i = blockIdx.x * 256 + threadIdx.x;     // 196608
  int j = i & 7, l = (i >> 3) & 63, kt = (i >> 9) & 7, nt = i >> 12;
  int n = nt * 16 + (l & 15);
  int k = kt * 32 + (l >> 4) * 8 + j;
  whhb[i] = f2bf(whh[n * 256 + k]);
}

// Wcomb[g][c] = gru_wih[g]@mh_w[:,c]; b1[g] = gru_bih[g] + wih[g]@mh_b
__global__ __launch_bounds__(256) void k_pcomb(const float* __restrict__ wih,
                                               const float* __restrict__ mh_w,
                                               const float* __restrict__ mh_b,
                                               const float* __restrict__ bih,
                                               float* __restrict__ Wcomb,
                                               float* __restrict__ b1) {
  int g0 = blockIdx.x * 8, t = threadIdx.x;
  float acc[8] = {0.f, 0.f, 0.f, 0.f, 0.f, 0.f, 0.f, 0.f};
  for (int j = 0; j < 256; ++j) {
    float wv = mh_w[j * 256 + t];
#pragma unroll
    for (int r = 0; r < 8; ++r) acc[r] += wih[(g0 + r) * 256 + j] * wv;
  }
#pragma unroll
  for (int r = 0; r < 8; ++r) Wcomb[(g0 + r) * 256 + t] = acc[r];
  __shared__ float red[4][8];
  float mb = mh_b[t];
#pragma unroll
  for (int r = 0; r < 8; ++r) {
    float v = wih[(g0 + r) * 256 + t] * mb;
    v += __shfl_down(v, 32); v += __shfl_down(v, 16); v += __shfl_down(v, 8);
    v += __shfl_down(v, 4);  v += __shfl_down(v, 2);  v += __shfl_down(v, 1);
    if ((t & 63) == 0) red[t >> 6][r] = v;
  }
  __syncthreads();
  if (t < 8) b1[g0 + t] = bih[g0 + t] + red[0][t] + red[1][t] + red[2][t] + red[3][t];
}

// Fold lags/weather/event/text projections through merge_w.
__global__ __launch_bounds__(256) void k_pmerge(const float* __restrict__ merge_w,
                                                const float* __restrict__ text_w,
                                                const float* __restrict__ lags_w,
                                                const float* __restrict__ weather_w,
                                                const float* __restrict__ event_w,
                                                const float* __restrict__ lags_b,
                                                const float* __restrict__ weather_b,
                                                const float* __restrict__ event_b,
                                                const float* __restrict__ text_b,
                                                float* __restrict__ MtxT,
                                                float* __restrict__ A_l,
                                                float* __restrict__ MwT,
                                                float* __restrict__ MeT,
                                                float* __restrict__ bias_deg) {
  int blk = blockIdx.x, t = threadIdx.x;
  if (blk < 128) {
    int c = blk;
    float acc = 0.f;
    for (int j = 0; j < 256; ++j)
      acc += merge_w[t * 1024 + 768 + j] * text_w[j * 128 + c];
    MtxT[c * 256 + t] = acc;
  } else {
    float a = 0.f, w0 = 0.f, w1 = 0.f, e0 = 0.f, e1 = 0.f, e2 = 0.f, e3 = 0.f, bd = 0.f;
    for (int j = 0; j < 256; ++j) {
      float m0 = merge_w[t * 1024 + j];
      float m1 = merge_w[t * 1024 + 256 + j];
      float m2 = merge_w[t * 1024 + 512 + j];
      float m3 = merge_w[t * 1024 + 768 + j];
      a  += m0 * lags_w[j];
      w0 += m1 * weather_w[j * 2 + 0];
      w1 += m1 * weather_w[j * 2 + 1];
      e0 += m2 * event_w[j * 4 + 0];
      e1 += m2 * event_w[j * 4 + 1];
      e2 += m2 * event_w[j * 4 + 2];
      e3 += m2 * event_w[j * 4 + 3];
      bd += m0 * lags_b[j] + m1 * weather_b[j] + m2 * event_b[j] + m3 * text_b[j];
    }
    A_l[t] = a;
    MwT[t] = w0; MwT[256 + t] = w1;
    MeT[t] = e0; MeT[256 + t] = e1; MeT[512 + t] = e2; MeT[768 + t] = e3;
    bias_deg[t] = bd;
  }
}

// ---------------------------------------------------------------------------
// MFMA textCNN: 2 waves/block, one node/block. Wave w owns channels
// c in [64w, 64w+64) (4 n-tiles). sx/sc3 shared (aliased union, 13.3KB).
// (R10 version — proven 154us, kept unchanged.)
// ---------------------------------------------------------------------------

#define LOADB4(DST, SRC, KT)                                                   \
  _Pragma("unroll") for (int q = 0; q < 4; ++q)                                \
      DST[q] = *(const short8v*)&SRC[((((KT) * 8 + NB + q) * 64) + l) * 8];

#define AFRAG3(AF, KT) {                                                       \
    const int kk_ = (KT) >> 1;                                                 \
    const int eb_ = 4 * ((KT) & 1) + g;                                        \
    _Pragma("unroll") for (int mt = 0; mt < 3; ++mt) {                         \
      int pr_ = 16 * mt + lr + kk_;                                            \
      int bb_ = eb_ ^ (pr_ & 7);                                               \
      AF[mt] = *(const short8v*)&sx[pr_ * 64 + bb_ * 8];                       \
    } }

#define AFRAG4(AF, KT) {                                                       \
    const int t4_ = 4 * (KT) + g;                                              \
    const int kk_ = t4_ >> 4;                                                  \
    const int bk_ = t4_ & 15;                                                  \
    _Pragma("unroll") for (int mt = 0; mt < 3; ++mt) {                         \
      int pr_ = 16 * mt + lr + kk_;                                            \
      int bb_ = (bk_ & 8) | ((bk_ ^ pr_) & 7);                                 \
      AF[mt] = *(const short8v*)&sc3[pr_ * 128 + bb_ * 8];                     \
    } }

#define MSTEP4(AF, BF)                                                         \
  _Pragma("unroll") for (int q = 0; q < 4; ++q)                                \
    _Pragma("unroll") for (int mt = 0; mt < 3; ++mt)                           \
      acc[mt][q] = MFMA16(AF[mt], BF[q], acc[mt][q], 0, 0, 0);

__global__ __launch_bounds__(128) void k_textcnn(const int* __restrict__ text,
                                                 const float* __restrict__ emb,
                                                 const u16* __restrict__ w3b,
                                                 const float* __restrict__ b3,
                                                 const u16* __restrict__ w4b,
                                                 const float* __restrict__ b4,
                                                 float* __restrict__ mx_g) {
  __shared__ u16 sbuf[52 * 128];      // union: sx (3200 u16) | sc3 (6656 u16)
  u16* sx = sbuf;
  u16* sc3 = sbuf;
  const int n = blockIdx.x;
  const int t = threadIdx.x;          // 0..127
  const int wv = t >> 6;              // wave 0/1
  const int l = t & 63;
  const int lr = l & 15;
  const int g = l >> 4;
  const int NB = wv * 4;              // n-tile base

  // ---- stage emb -> sx (bf16, swizzled); wave wv stages s in [25wv,25wv+25) ----
  int idxv = (l < 25) ? text[n * 50 + wv * 25 + l] : 0;
  const int e = l;
#pragma unroll 5
  for (int si = 0; si < 25; ++si) {
    int s = wv * 25 + si;
    int id = __shfl(idxv, si);
    float v = (e < 50) ? emb[id * 50 + e] : 0.f;
    int bb = (e >> 3) ^ (s & 7);
    sx[s * 64 + bb * 8 + (e & 7)] = f2bf(v);
  }
  __syncthreads();

  const float4v zv = {0.f, 0.f, 0.f, 0.f};
  float4v acc[3][4];
#pragma unroll
  for (int mt = 0; mt < 3; ++mt)
#pragma unroll
    for (int q = 0; q < 4; ++q) acc[mt][q] = zv;

  float b3v[4];
#pragma unroll
  for (int q = 0; q < 4; ++q) b3v[q] = b3[(NB + q) * 16 + lr];

  // ---- conv3: 6 k-tiles, B double-buffered in regs ----
  {
    short8v bA[4], bB[4], a[3];
    LOADB4(bA, w3b, 0);
    for (int kt = 0; kt < 6; kt += 2) {
      LOADB4(bB, w3b, kt + 1);
      AFRAG3(a, kt);
      MSTEP4(a, bA);
      if (kt + 2 < 6) LOADB4(bA, w3b, kt + 2);
      AFRAG3(a, kt + 1);
      MSTEP4(a, bB);
    }
  }
  __syncthreads();   // both waves' sx reads done before sc3 overwrites (aliased)

  // ---- bias+relu+cvt -> sc3 (swizzled); re-zero acc ----
#pragma unroll
  for (int mt = 0; mt < 3; ++mt)
#pragma unroll
    for (int q = 0; q < 4; ++q) {
#pragma unroll
      for (int r = 0; r < 4; ++r) {
        int p = 16 * mt + 4 * g + r;
        int c = (NB + q) * 16 + lr;
        float v = fmaxf(acc[mt][q][r] + b3v[q], 0.f);
        int bb = (c >> 3) & 15;
        bb = (bb & 8) | ((bb ^ (p & 7)) & 7);
        sc3[p * 128 + bb * 8 + (c & 7)] = f2bf(v);
      }
      acc[mt][q] = zv;
    }
  __syncthreads();

  // ---- conv4: 16 k-tiles ----
  {
    short8v bA[4], bB[4], a[3];
    LOADB4(bA, w4b, 0);
    for (int kt = 0; kt < 16; kt += 2) {
      LOADB4(bB, w4b, kt + 1);
      AFRAG4(a, kt);
      MSTEP4(a, bA);
      if (kt + 2 < 16) LOADB4(bA, w4b, kt + 2);
      AFRAG4(a, kt + 1);
      MSTEP4(a, bB);
    }
  }

  // ---- max over valid p (<45), +bias, relu, store ----
#pragma unroll
  for (int q = 0; q < 4; ++q) {
    float m0 = -1e30f;
#pragma unroll
    for (int mt = 0; mt < 3; ++mt)
#pragma unroll
      for (int r = 0; r < 4; ++r) {
        int p = 16 * mt + 4 * g + r;
        if (p < 45) m0 = fmaxf(m0, acc[mt][q][r]);
      }
    m0 = fmaxf(m0, __shfl_xor(m0, 16));
    m0 = fmaxf(m0, __shfl_xor(m0, 32));
    int c = (NB + q) * 16 + lr;
    float bias = b4[c];
    if (g == 0) mx_g[n * 128 + c] = fmaxf(m0 + bias, 0.f);
  }
}

__device__ inline void preds_of(int i, int& p1, int& p2, int& d) {
  int tt = i % 10;
  int base = i - tt;
  if (tt == 0)      { p1 = base + 9;      p2 = -1;             d = 1; }
  else if (tt == 1) { p1 = base;          p2 = -1;             d = 1; }
  else              { p1 = base + tt - 2; p2 = base + tt - 1;  d = 2; }
}

// graph agg + folded merge -> m_bf[N][256] (bf16, pre-BN, relu'd) + BN sums
__global__ __launch_bounds__(256) void k_merge(const float* __restrict__ mx_g,
                                               const float* __restrict__ lags,
                                               const float* __restrict__ weather,
                                               const float* __restrict__ event,
                                               const float* __restrict__ MtxT,
                                               const float* __restrict__ A_l,
                                               const float* __restrict__ MwT,
                                               const float* __restrict__ MeT,
                                               const float* __restrict__ bias_deg,
                                               const float* __restrict__ merge_b,
                                               u16* __restrict__ m_bf,
                                               float* __restrict__ bnsum,
                                               float* __restrict__ bnsumsq) {
  __shared__ __align__(16) float mxs[16 * 128];
  __shared__ float scal[16 * 8];
  const int tid = threadIdx.x;
  const int row0 = blockIdx.x * 16;
  for (int idx = tid; idx < 2048; idx += 256) {
    int r = idx >> 7, c = idx & 127;
    int p1, p2, d;
    preds_of(row0 + r, p1, p2, d);
    float v = mx_g[p1 * 128 + c];
    if (p2 >= 0) v += mx_g[p2 * 128 + c];
    mxs[r * 128 + c] = v;
  }
  if (tid < 16) {
    int p1, p2, d;
    preds_of(row0 + tid, p1, p2, d);
    float sl = lags[p1];
    float sw0 = weather[p1 * 2], sw1 = weather[p1 * 2 + 1];
    float se0 = event[p1 * 4], se1 = event[p1 * 4 + 1];
    float se2 = event[p1 * 4 + 2], se3 = event[p1 * 4 + 3];
    if (p2 >= 0) {
      sl += lags[p2];
      sw0 += weather[p2 * 2]; sw1 += weather[p2 * 2 + 1];
      se0 += event[p2 * 4];     se1 += event[p2 * 4 + 1];
      se2 += event[p2 * 4 + 2]; se3 += event[p2 * 4 + 3];
    }
    scal[tid * 8 + 0] = sl;
    scal[tid * 8 + 1] = sw0; scal[tid * 8 + 2] = sw1;
    scal[tid * 8 + 3] = se0; scal[tid * 8 + 4] = se1;
    scal[tid * 8 + 5] = se2; scal[tid * 8 + 6] = se3;
    scal[tid * 8 + 7] = (float)d;
  }
  __syncthreads();
  const int t = tid;
  float acc[16];
#pragma unroll
  for (int r = 0; r < 16; ++r) acc[r] = 0.f;
  for (int c4 = 0; c4 < 32; ++c4) {
    const int c = c4 * 4;
    float w0 = MtxT[c * 256 + t];
    float w1 = MtxT[(c + 1) * 256 + t];
    float w2 = MtxT[(c + 2) * 256 + t];
    float w3 = MtxT[(c + 3) * 256 + t];
#pragma unroll
    for (int r = 0; r < 16; ++r) {
      float4 mv = *(const float4*)&mxs[r * 128 + c];
      acc[r] += mv.x * w0 + mv.y * w1 + mv.z * w2 + mv.w * w3;
    }
  }
  float al = A_l[t], mw0 = MwT[t], mw1 = MwT[256 + t];
  float me0 = MeT[t], me1 = MeT[256 + t], me2 = MeT[512 + t], me3 = MeT[768 + t];
  float bd = bias_deg[t], mb = merge_b[t];
  float s1 = 0.f, s2 = 0.f;
#pragma unroll
  for (int r = 0; r < 16; ++r) {
    float mp = acc[r] + scal[r * 8] * al + scal[r * 8 + 1] * mw0 + scal[r * 8 + 2] * mw1
             + scal[r * 8 + 3] * me0 + scal[r * 8 + 4] * me1 + scal[r * 8 + 5] * me2
             + scal[r * 8 + 6] * me3 + scal[r * 8 + 7] * bd + mb;
    float mv = fmaxf(mp, 0.f);
    m_bf[(row0 + r) * 256 + t] = f2bf(mv);
    s1 += mv;
    s2 += mv * mv;
  }
  atomicAdd(&bnsum[t], s1);
  atomicAdd(&bnsumsq[t], s2);
}

__global__ __launch_bounds__(256) void k_bna(const float* __restrict__ bnsum,
                                             const float* __restrict__ bnsumsq,
                                             const float* __restrict__ gamma,
                                             const float* __restrict__ beta,
                                             float* __restrict__ svec,
                                             float* __restrict__ tvec) {
  int c = threadIdx.x;
  float mu = bnsum[c] * (1.f / 10240.f);
  float var = bnsumsq[c] * (1.f / 10240.f) - mu * mu;
  float s = gamma[c] * rsqrtf(var + 1e-5f);
  svec[c] = s;
  tvec[c] = beta[c] - mu * s;
}

// blocks 0..767: wbig_b (bf16 frag-linear, BN scale folded)
// blocks 768..1535: bias_big[g] = b1[g] + tvec@Wcomb[g]
__global__ __launch_bounds__(256) void k_bnbc(const float* __restrict__ Wcomb,
                                              const float* __restrict__ svec,
                                              const float* __restrict__ tvec,
                                              const float* __restrict__ b1,
                                              u16* __restrict__ wbig_b,
                                              float* __restrict__ bias_big) {
  int blk = blockIdx.x, t = threadIdx.x;
  __shared__ float red[4];
  if (blk < 768) {
    int i = blk * 256 + t;
    int j = i & 7, l = (i >> 3) & 63, kt = (i >> 9) & 7, nt = i >> 12;
    int n = nt * 16 + (l & 15);
    int k = kt * 32 + (l >> 4) * 8 + j;
    wbig_b[i] = f2bf(Wcomb[n * 256 + k] * svec[k]);
  } else {
    int gg = blk - 768;
    float part = tvec[t] * Wcomb[gg * 256 + t];
    part += __shfl_down(part, 32); part += __shfl_down(part, 16);
    part += __shfl_down(part, 8);  part += __shfl_down(part, 4);
    part += __shfl_down(part, 2);  part += __shfl_down(part, 1);
    if ((t & 63) == 0) red[t >> 6] = part;
    __syncthreads();
    if (t == 0) bias_big[gg] = b1[gg] + red[0] + red[1] + red[2] + red[3];
  }
}

// gi[N][768] = m @ Wbig^T + bias_big  (bf16 MFMA; BN+mh+Wih folded)
// 640 blocks x 16 rows; wave w owns nt in [w*12, w*12+12)
__global__ __launch_bounds__(256) void k_gi(const u16* __restrict__ m_bf,
                                            const u16* __restrict__ wbig_b,
                                            const float* __restrict__ bias_big,
                                            float* __restrict__ gi) {
  const int t = threadIdx.x;
  const int w = t >> 6, l = t & 63, lr = l & 15, g = l >> 4;
  const int row0 = blockIdx.x * 16;
  short8v a[8];
#pragma unroll
  for (int kt = 0; kt < 8; ++kt)
    a[kt] = *(const short8v*)&m_bf[(row0 + lr) * 256 + kt * 32 + g * 8];
  const float4v zv = {0.f, 0.f, 0.f, 0.f};
  float4v acc[12];
#pragma unroll
  for (int j = 0; j < 12; ++j) acc[j] = zv;
#pragma unroll 2
  for (int kt = 0; kt < 8; ++kt) {
#pragma unroll
    for (int j = 0; j < 12; ++j) {
      int nt = w * 12 + j;
      short8v b = *(const short8v*)&wbig_b[((nt * 8 + kt) * 64 + l) * 8];
      acc[j] = MFMA16(a[kt], b, acc[j], 0, 0, 0);
    }
  }
#pragma unroll
  for (int j = 0; j < 12; ++j) {
    int col = (w * 12 + j) * 16 + lr;
    float bb = bias_big[col];
#pragma unroll
    for (int r = 0; r < 4; ++r)
      gi[(row0 + g * 4 + r) * 768 + col] = acc[j][r] + bb;
  }
}

// ---------------------------------------------------------------------------
// Fused GRU, all 10 steps. 64 blocks x 16 rows x 8 waves (2/SIMD).
// Wave w owns colblks {2w, 2w+1}; nt = gate*16 + 2w + i keeps each lane's
// (r,z,n) triple in-register. h: bf16 swizzled LDS + f32 regs.
// ---------------------------------------------------------------------------
__global__ __launch_bounds__(512) void k_gru_all(const float* __restrict__ gi,
                                                 const u16* __restrict__ whhb,
                                                 const float* __restrict__ bhh,
                                                 const float* __restrict__ reg_w,
                                                 const float* __restrict__ reg_b,
                                                 float* __restrict__ out) {
  __shared__ u16 hb[16 * 256];
  __shared__ float red[8][16];
  const int t = threadIdx.x;
  const int w = t >> 6, l = t & 63, lr = l & 15, g = l >> 4;
  const int row0 = blockIdx.x * 16;
  for (int i = t; i < 4096; i += 512) hb[i] = 0;
  float hp[2][4];                    // [i][r] : h(row g*4+r, col (2w+i)*16+lr)
#pragma unroll
  for (int i = 0; i < 2; ++i)
#pragma unroll
    for (int r = 0; r < 4; ++r) hp[i][r] = 0.f;
  float bh[3][2];
#pragma unroll
  for (int gate = 0; gate < 3; ++gate)
#pragma unroll
    for (int i = 0; i < 2; ++i)
      bh[gate][i] = bhh[gate * 256 + (2 * w + i) * 16 + lr];
  float racc[4] = {0.f, 0.f, 0.f, 0.f};

  for (int s = 0; s < 10; ++s) {
    __syncthreads();                 // hb (init or prev-step writes) visible
    const float4v zv = {0.f, 0.f, 0.f, 0.f};
    float4v acc[3][2];
#pragma unroll
    for (int gate = 0; gate < 3; ++gate)
#pragma unroll
      for (int i = 0; i < 2; ++i) acc[gate][i] = zv;
#pragma unroll
    for (int kt = 0; kt < 8; ++kt) {
      int kb = kt * 4 + g;
      int bb = kb ^ (lr & 7);
      short8v a = *(const short8v*)&hb[lr * 256 + bb * 8];
#pragma unroll
      for (int gate = 0; gate < 3; ++gate)
#pragma unroll
        for (int i = 0; i < 2; ++i) {
          int nt = gate * 16 + 2 * w + i;
          short8v b = *(const short8v*)&whhb[((nt * 8 + kt) * 64 + l) * 8];
          acc[gate][i] = MFMA16(a, b, acc[gate][i], 0, 0, 0);
        }
    }
    __syncthreads();                 // all hb reads done before overwrite
#pragma unroll
    for (int i = 0; i < 2; ++i) {
      int c = (2 * w + i) * 16 + lr;
      float rwv = reg_w[s * 256 + c];
#pragma unroll
      for (int r = 0; r < 4; ++r) {
        int node = (row0 + g * 4 + r) * 10 + s;
        float gir = gi[node * 768 + c];
        float giz = gi[node * 768 + 256 + c];
        float gin = gi[node * 768 + 512 + c];
        float ghr = acc[0][i][r] + bh[0][i];
        float ghz = acc[1][i][r] + bh[1][i];
        float ghn = acc[2][i][r] + bh[2][i];
        float rg = 1.f / (1.f + expf(-(gir + ghr)));
        float zg = 1.f / (1.f + expf(-(giz + ghz)));
        float ng = tanhf(gin + rg * ghn);
        float hn = (1.f - zg) * ng + zg * hp[i][r];
        hp[i][r] = hn;
        racc[r] += hn * rwv;
        int m = g * 4 + r;
        int bb2 = (c >> 3) ^ (m & 7);
        hb[m * 256 + bb2 * 8 + (c & 7)] = f2bf(hn);
      }
    }
  }
#pragma unroll
  for (int r = 0; r < 4; ++r) {
    float v = racc[r];
    v += __shfl_xor(v, 1); v += __shfl_xor(v, 2);
    v += __shfl_xor(v, 4); v += __shfl_xor(v, 8);
    racc[r] = v;
  }
  if (lr == 0) {
#pragma unroll
    for (int r = 0; r < 4; ++r) red[w][g * 4 + r] = racc[r];
  }
  __syncthreads();
  if (t < 16) {
    float sum = reg_b[0];
#pragma unroll
    for (int w8 = 0; w8 < 8; ++w8) sum += red[w8][t];
    out[row0 + t] = sum;
  }
}

extern "C" void kernel_launch(void* const* d_in, const int* in_sizes, int n_in,
                              void* d_out, int out_size, void* d_ws, size_t ws_size,
                              hipStream_t stream) {
  (void)in_sizes; (void)n_in; (void)out_size; (void)ws_size;
  const float* lags      = (const float*)d_in[0];
  const float* weather   = (const float*)d_in[1];
  const float* event     = (const float*)d_in[2];
  const int*   text      = (const int*)d_in[3];
  const float* emb       = (const float*)d_in[4];
  const float* conv3_w   = (const float*)d_in[5];
  const float* conv3_b   = (const float*)d_in[6];
  const float* conv4_w   = (const float*)d_in[7];
  const float* conv4_b   = (const float*)d_in[8];
  const float* lags_w    = (const float*)d_in[9];
  const float* lags_b    = (const float*)d_in[10];
  const float* weather_w = (const float*)d_in[11];
  const float* weather_b = (const float*)d_in[12];
  const float* event_w   = (const float*)d_in[13];
  const float* event_b   = (const float*)d_in[14];
  const float* text_w    = (const float*)d_in[15];
  const float* text_b    = (const float*)d_in[16];
  const float* merge_w   = (const float*)d_in[17];
  const float* merge_b   = (const float*)d_in[18];
  const float* bn_gamma  = (const float*)d_in[19];
  const float* bn_beta   = (const float*)d_in[20];
  const float* mh_w      = (const float*)d_in[21];
  const float* mh_b      = (const float*)d_in[22];
  const float* gru_wih   = (const float*)d_in[23];
  const float* gru_whh   = (const float*)d_in[24];
  const float* gru_bih   = (const float*)d_in[25];
  const float* gru_bhh   = (const float*)d_in[26];
  const float* reg_w     = (const float*)d_in[27];
  const float* reg_b     = (const float*)d_in[28];
  float* out = (float*)d_out;

  float* p = (float*)d_ws;
  float* bnsum    = p; p += 256;            // zeroed
  float* bnsumsq  = p; p += 256;            // zeroed
  float* mx       = p; p += 10240 * 128;
  u16*   m_bf     = (u16*)p; p += 10240 * 128;   // 10240*256 u16
  float* gi       = p; p += 10240 * 768;
  u16*   w3b      = (u16*)p; p += 12288;    // 24576 u16
  u16*   w4b      = (u16*)p; p += 32768;    // 65536 u16
  u16*   whhb     = (u16*)p; p += 98304;    // 196608 u16
  u16*   wbig_b   = (u16*)p; p += 98304;    // 196608 u16
  float* Wcomb    = p; p += 196608;
  float* MtxT     = p; p += 32768;
  float* A_l      = p; p += 256;
  float* MwT      = p; p += 512;
  float* MeT      = p; p += 1024;
  float* bias_deg = p; p += 256;
  float* b1       = p; p += 768;
  float* bias_big = p; p += 768;
  float* svec     = p; p += 256;
  float* tvec     = p; p += 256;

  k_zero<<<dim3(2), dim3(256), 0, stream>>>(bnsum, 512);
  k_repb3<<<dim3(96), dim3(256), 0, stream>>>(conv3_w, w3b);
  k_repb4<<<dim3(256), dim3(256), 0, stream>>>(conv4_w, w4b);
  k_repwhh<<<dim3(768), dim3(256), 0, stream>>>(gru_whh, whhb);
  k_pcomb<<<dim3(96), dim3(256), 0, stream>>>(gru_wih, mh_w, mh_b, gru_bih, Wcomb, b1);
  k_pmerge<<<dim3(129), dim3(256), 0, stream>>>(merge_w, text_w, lags_w, weather_w, event_w,
                                                lags_b, weather_b, event_b, text_b,
                                                MtxT, A_l, MwT, MeT, bias_deg);
  k_textcnn<<<dim3(10240), dim3(128), 0, stream>>>(text, emb, w3b, conv3_b, w4b, conv4_b, mx);
  k_merge<<<dim3(640), dim3(256), 0, stream>>>(mx, lags, weather, event, MtxT, A_l, MwT, MeT,
                                               bias_deg, merge_b, m_bf, bnsum, bnsumsq);
  k_bna<<<dim3(1), dim3(256), 0, stream>>>(bnsum, bnsumsq, bn_gamma, bn_beta, svec, tvec);
  k_bnbc<<<dim3(1536), dim3(256), 0, stream>>>(Wcomb, svec, tvec, b1, wbig_b, bias_big);
  k_gi<<<dim3(640), dim3(256), 0, stream>>>(m_bf, wbig_b, bias_big, gi);
  k_gru_all<<<dim3(64), dim3(512), 0, stream>>>(gi, whhb, gru_bhh, reg_w, reg_b, out);
}

// Round 13
// 544.256 us; speedup vs baseline: 1.2311x; 1.0374x over previous
//
#include <hip/hip_runtime.h>
#include <math.h>

// ---------------------------------------------------------------------------
// Model dims: BS=1024 T=10 H=256 C=128 E=50 SEQ=50 V=50000 NREG=1
// R12 = R11 (565us) + (a) k_tr + coalesced k_pmerge [bisection step 3 — last
//   R4 delta; merge_w lane-stride-4KB reads cost ~60-80us of L2 traffic] and
//   (b) textcnn 2->4 waves/block [extends R10's proven TLP lever; math
//   identical]. mwT aliases mx (R8 scheme, footprint stays 43.85MB).
// ---------------------------------------------------------------------------

typedef unsigned short u16;
typedef __attribute__((ext_vector_type(8))) short short8v;   // 8 bf16 = 4 VGPR
typedef __attribute__((ext_vector_type(4))) float float4v;
#define MFMA16 __builtin_amdgcn_mfma_f32_16x16x32_bf16

__device__ inline u16 f2bf(float f) {
  unsigned u = __float_as_uint(f);
  u += 0x7FFFu + ((u >> 16) & 1u);            // RNE
  return (u16)(u >> 16);
}

__global__ __launch_bounds__(256) void k_zero(float* __restrict__ p, int n) {
  int i = blockIdx.x * 256 + threadIdx.x;
  if (i < n) p[i] = 0.f;
}

// conv3 weights [c=128][e=50][kk=3] -> frag-linear B: [kt=6][nt=8][lane=64][j=8]
__global__ __launch_bounds__(256) void k_repb3(const float* __restrict__ w3,
                                               u16* __restrict__ w3b) {
  int i = blockIdx.x * 256 + threadIdx.x;     // 24576
  if (i >= 24576) return;
  int j = i & 7, l = (i >> 3) & 63, nt = (i >> 9) & 7, kt = i >> 12;
  int k = kt * 32 + (l >> 4) * 8 + j;
  int c = nt * 16 + (l & 15);
  int kk = k >> 6, e = k & 63;
  float v = (e < 50) ? w3[c * 150 + e * 3 + kk] : 0.f;
  w3b[i] = f2bf(v);
}

// conv4 weights [c=128][ci=128][kk=4] -> frag-linear B: [kt=16][nt=8][lane][j]
__global__ __launch_bounds__(256) void k_repb4(const float* __restrict__ w4,
                                               u16* __restrict__ w4b) {
  int i = blockIdx.x * 256 + threadIdx.x;     // 65536
  int j = i & 7, l = (i >> 3) & 63, nt = (i >> 9) & 7, kt = i >> 12;
  int k = kt * 32 + (l >> 4) * 8 + j;
  int c = nt * 16 + (l & 15);
  int kk = k >> 7, ci = k & 127;
  w4b[i] = f2bf(w4[c * 512 + ci * 4 + kk]);
}

// gru_whh [768][256] -> bf16 frag-linear B for gh GEMM: B[k][n]=whh[n][k]
__global__ __launch_bounds__(256) void k_repwhh(const float* __restrict__ whh,
                                                u16* __restrict__ whhb) {
  int i = blockIdx.x * 256 + threadIdx.x;     // 196608
  int j = i & 7, l = (i >> 3) & 63, kt = (i >> 9) & 7, nt = i >> 12;
  int n = nt * 16 + (l & 15);
  int k = kt * 32 + (l >> 4) * 8 + j;
  whhb[i] = f2bf(whh[n * 256 + k]);
}

// merge_w [256][1024] -> mwT [1024][256] (coalesced tile transpose)
__global__ __launch_bounds__(256) void k_tr(const float* __restrict__ A,
                                            float* __restrict__ AT) {
  __shared__ float tile[32][33];
  int bx = blockIdx.x;               // 32 col-tiles
  int by = blockIdx.y;               // 8 row-tiles
  int lx = threadIdx.x & 31, ly = threadIdx.x >> 5;
#pragma unroll
  for (int i = 0; i < 4; ++i)
    tile[ly + i * 8][lx] = A[(by * 32 + ly + i * 8) * 1024 + bx * 32 + lx];
  __syncthreads();
#pragma unroll
  for (int i = 0; i < 4; ++i)
    AT[(bx * 32 + ly + i * 8) * 256 + by * 32 + lx] = tile[lx][ly + i * 8];
}

// Wcomb[g][c] = gru_wih[g]@mh_w[:,c]; b1[g] = gru_bih[g] + wih[g]@mh_b
__global__ __launch_bounds__(256) void k_pcomb(const float* __restrict__ wih,
                                               const float* __restrict__ mh_w,
                                               const float* __restrict__ mh_b,
                                               const float* __restrict__ bih,
                                               float* __restrict__ Wcomb,
                                               float* __restrict__ b1) {
  int g0 = blockIdx.x * 8, t = threadIdx.x;
  float acc[8] = {0.f, 0.f, 0.f, 0.f, 0.f, 0.f, 0.f, 0.f};
  for (int j = 0; j < 256; ++j) {
    float wv = mh_w[j * 256 + t];
#pragma unroll
    for (int r = 0; r < 8; ++r) acc[r] += wih[(g0 + r) * 256 + j] * wv;
  }
#pragma unroll
  for (int r = 0; r < 8; ++r) Wcomb[(g0 + r) * 256 + t] = acc[r];
  __shared__ float red[4][8];
  float mb = mh_b[t];
#pragma unroll
  for (int r = 0; r < 8; ++r) {
    float v = wih[(g0 + r) * 256 + t] * mb;
    v += __shfl_down(v, 32); v += __shfl_down(v, 16); v += __shfl_down(v, 8);
    v += __shfl_down(v, 4);  v += __shfl_down(v, 2);  v += __shfl_down(v, 1);
    if ((t & 63) == 0) red[t >> 6][r] = v;
  }
  __syncthreads();
  if (t < 8) b1[g0 + t] = bih[g0 + t] + red[0][t] + red[1][t] + red[2][t] + red[3][t];
}

// Fold lags/weather/event/text projections through merge_w (reads mwT, coalesced).
__global__ __launch_bounds__(256) void k_pmerge(const float* __restrict__ mwT,
                                                const float* __restrict__ text_w,
                                                const float* __restrict__ lags_w,
                                                const float* __restrict__ weather_w,
                                                const float* __restrict__ event_w,
                                                const float* __restrict__ lags_b,
                                                const float* __restrict__ weather_b,
                                                const float* __restrict__ event_b,
                                                const float* __restrict__ text_b,
                                                float* __restrict__ MtxT,
                                                float* __restrict__ A_l,
                                                float* __restrict__ MwT,
                                                float* __restrict__ MeT,
                                                float* __restrict__ bias_deg) {
  int blk = blockIdx.x, t = threadIdx.x;
  if (blk < 128) {
    int c = blk;
    float acc = 0.f;
    for (int j = 0; j < 256; ++j)
      acc += mwT[(768 + j) * 256 + t] * text_w[j * 128 + c];
    MtxT[c * 256 + t] = acc;
  } else {
    float a = 0.f, w0 = 0.f, w1 = 0.f, e0 = 0.f, e1 = 0.f, e2 = 0.f, e3 = 0.f, bd = 0.f;
    for (int j = 0; j < 256; ++j) {
      float m0 = mwT[j * 256 + t];
      float m1 = mwT[(256 + j) * 256 + t];
      float m2 = mwT[(512 + j) * 256 + t];
      float m3 = mwT[(768 + j) * 256 + t];
      a  += m0 * lags_w[j];
      w0 += m1 * weather_w[j * 2 + 0];
      w1 += m1 * weather_w[j * 2 + 1];
      e0 += m2 * event_w[j * 4 + 0];
      e1 += m2 * event_w[j * 4 + 1];
      e2 += m2 * event_w[j * 4 + 2];
      e3 += m2 * event_w[j * 4 + 3];
      bd += m0 * lags_b[j] + m1 * weather_b[j] + m2 * event_b[j] + m3 * text_b[j];
    }
    A_l[t] = a;
    MwT[t] = w0; MwT[256 + t] = w1;
    MeT[t] = e0; MeT[256 + t] = e1; MeT[512 + t] = e2; MeT[768 + t] = e3;
    bias_deg[t] = bd;
  }
}

// ---------------------------------------------------------------------------
// MFMA textCNN: 4 waves/block, one node/block. Wave w owns channels
// c in [32w, 32w+32) (2 n-tiles). sx/sc3 shared (aliased union, 13.3KB).
// ---------------------------------------------------------------------------

#define LOADB2(DST, SRC, KT)                                                   \
  _Pragma("unroll") for (int q = 0; q < 2; ++q)                                \
      DST[q] = *(const short8v*)&SRC[((((KT) * 8 + NB + q) * 64) + l) * 8];

#define AFRAG3(AF, KT) {                                                       \
    const int kk_ = (KT) >> 1;                                                 \
    const int eb_ = 4 * ((KT) & 1) + g;                                        \
    _Pragma("unroll") for (int mt = 0; mt < 3; ++mt) {                         \
      int pr_ = 16 * mt + lr + kk_;                                            \
      int bb_ = eb_ ^ (pr_ & 7);                                               \
      AF[mt] = *(const short8v*)&sx[pr_ * 64 + bb_ * 8];                       \
    } }

#define AFRAG4(AF, KT) {                                                       \
    const int t4_ = 4 * (KT) + g;                                              \
    const int kk_ = t4_ >> 4;                                                  \
    const int bk_ = t4_ & 15;                                                  \
    _Pragma("unroll") for (int mt = 0; mt < 3; ++mt) {                         \
      int pr_ = 16 * mt + lr + kk_;                                            \
      int bb_ = (bk_ & 8) | ((bk_ ^ pr_) & 7);                                 \
      AF[mt] = *(const short8v*)&sc3[pr_ * 128 + bb_ * 8];                     \
    } }

#define MSTEP2(AF, BF)                                                         \
  _Pragma("unroll") for (int q = 0; q < 2; ++q)                                \
    _Pragma("unroll") for (int mt = 0; mt < 3; ++mt)                           \
      acc[mt][q] = MFMA16(AF[mt], BF[q], acc[mt][q], 0, 0, 0);

__global__ __launch_bounds__(256) void k_textcnn(const int* __restrict__ text,
                                                 const float* __restrict__ emb,
                                                 const u16* __restrict__ w3b,
                                                 const float* __restrict__ b3,
                                                 const u16* __restrict__ w4b,
                                                 const float* __restrict__ b4,
                                                 float* __restrict__ mx_g) {
  __shared__ u16 sbuf[52 * 128];      // union: sx (3200 u16) | sc3 (6656 u16)
  u16* sx = sbuf;
  u16* sc3 = sbuf;
  const int n = blockIdx.x;
  const int t = threadIdx.x;          // 0..255
  const int wv = t >> 6;              // wave 0..3
  const int l = t & 63;
  const int lr = l & 15;
  const int g = l >> 4;
  const int NB = wv * 2;              // n-tile base (2 tiles per wave)

  // ---- stage emb -> sx (bf16, swizzled); wave wv stages s ≡ wv (mod 4) ----
  int idxv = (l < 50) ? text[n * 50 + l] : 0;
  const int e = l;
  for (int s = wv; s < 50; s += 4) {
    int id = __shfl(idxv, s);
    float v = (e < 50) ? emb[id * 50 + e] : 0.f;
    int bb = (e >> 3) ^ (s & 7);
    sx[s * 64 + bb * 8 + (e & 7)] = f2bf(v);
  }
  __syncthreads();

  const float4v zv = {0.f, 0.f, 0.f, 0.f};
  float4v acc[3][2];
#pragma unroll
  for (int mt = 0; mt < 3; ++mt)
#pragma unroll
    for (int q = 0; q < 2; ++q) acc[mt][q] = zv;

  float b3v[2];
#pragma unroll
  for (int q = 0; q < 2; ++q) b3v[q] = b3[(NB + q) * 16 + lr];

  // ---- conv3: 6 k-tiles, B double-buffered in regs ----
  {
    short8v bA[2], bB[2], a[3];
    LOADB2(bA, w3b, 0);
    for (int kt = 0; kt < 6; kt += 2) {
      LOADB2(bB, w3b, kt + 1);
      AFRAG3(a, kt);
      MSTEP2(a, bA);
      if (kt + 2 < 6) LOADB2(bA, w3b, kt + 2);
      AFRAG3(a, kt + 1);
      MSTEP2(a, bB);
    }
  }
  __syncthreads();   // all waves' sx reads done before sc3 overwrites (aliased)

  // ---- bias+relu+cvt -> sc3 (swizzled); re-zero acc ----
#pragma unroll
  for (int mt = 0; mt < 3; ++mt)
#pragma unroll
    for (int q = 0; q < 2; ++q) {
#pragma unroll
      for (int r = 0; r < 4; ++r) {
        int p = 16 * mt + 4 * g + r;
        int c = (NB + q) * 16 + lr;
        float v = fmaxf(acc[mt][q][r] + b3v[q], 0.f);
        int bb = (c >> 3) & 15;
        bb = (bb & 8) | ((bb ^ (p & 7)) & 7);
        sc3[p * 128 + bb * 8 + (c & 7)] = f2bf(v);
      }
      acc[mt][q] = zv;
    }
  __syncthreads();

  // ---- conv4: 16 k-tiles ----
  {
    short8v bA[2], bB[2], a[3];
    LOADB2(bA, w4b, 0);
    for (int kt = 0; kt < 16; kt += 2) {
      LOADB2(bB, w4b, kt + 1);
      AFRAG4(a, kt);
      MSTEP2(a, bA);
      if (kt + 2 < 16) LOADB2(bA, w4b, kt + 2);
      AFRAG4(a, kt + 1);
      MSTEP2(a, bB);
    }
  }

  // ---- max over valid p (<45), +bias, relu, store ----
#pragma unroll
  for (int q = 0; q < 2; ++q) {
    float m0 = -1e30f;
#pragma unroll
    for (int mt = 0; mt < 3; ++mt)
#pragma unroll
      for (int r = 0; r < 4; ++r) {
        int p = 16 * mt + 4 * g + r;
        if (p < 45) m0 = fmaxf(m0, acc[mt][q][r]);
      }
    m0 = fmaxf(m0, __shfl_xor(m0, 16));
    m0 = fmaxf(m0, __shfl_xor(m0, 32));
    int c = (NB + q) * 16 + lr;
    float bias = b4[c];
    if (g == 0) mx_g[n * 128 + c] = fmaxf(m0 + bias, 0.f);
  }
}

__device__ inline void preds_of(int i, int& p1, int& p2, int& d) {
  int tt = i % 10;
  int base = i - tt;
  if (tt == 0)      { p1 = base + 9;      p2 = -1;             d = 1; }
  else if (tt == 1) { p1 = base;          p2 = -1;             d = 1; }
  else              { p1 = base + tt - 2; p2 = base + tt - 1;  d = 2; }
}

// graph agg + folded merge -> m_bf[N][256] (bf16, pre-BN, relu'd) + BN sums
__global__ __launch_bounds__(256) void k_merge(const float* __restrict__ mx_g,
                                               const float* __restrict__ lags,
                                               const float* __restrict__ weather,
                                               const float* __restrict__ event,
                                               const float* __restrict__ MtxT,
                                               const float* __restrict__ A_l,
                                               const float* __restrict__ MwT,
                                               const float* __restrict__ MeT,
                                               const float* __restrict__ bias_deg,
                                               const float* __restrict__ merge_b,
                                               u16* __restrict__ m_bf,
                                               float* __restrict__ bnsum,
                                               float* __restrict__ bnsumsq) {
  __shared__ __align__(16) float mxs[16 * 128];
  __shared__ float scal[16 * 8];
  const int tid = threadIdx.x;
  const int row0 = blockIdx.x * 16;
  for (int idx = tid; idx < 2048; idx += 256) {
    int r = idx >> 7, c = idx & 127;
    int p1, p2, d;
    preds_of(row0 + r, p1, p2, d);
    float v = mx_g[p1 * 128 + c];
    if (p2 >= 0) v += mx_g[p2 * 128 + c];
    mxs[r * 128 + c] = v;
  }
  if (tid < 16) {
    int p1, p2, d;
    preds_of(row0 + tid, p1, p2, d);
    float sl = lags[p1];
    float sw0 = weather[p1 * 2], sw1 = weather[p1 * 2 + 1];
    float se0 = event[p1 * 4], se1 = event[p1 * 4 + 1];
    float se2 = event[p1 * 4 + 2], se3 = event[p1 * 4 + 3];
    if (p2 >= 0) {
      sl += lags[p2];
      sw0 += weather[p2 * 2]; sw1 += weather[p2 * 2 + 1];
      se0 += event[p2 * 4];     se1 += event[p2 * 4 + 1];
      se2 += event[p2 * 4 + 2]; se3 += event[p2 * 4 + 3];
    }
    scal[tid * 8 + 0] = sl;
    scal[tid * 8 + 1] = sw0; scal[tid * 8 + 2] = sw1;
    scal[tid * 8 + 3] = se0; scal[tid * 8 + 4] = se1;
    scal[tid * 8 + 5] = se2; scal[tid * 8 + 6] = se3;
    scal[tid * 8 + 7] = (float)d;
  }
  __syncthreads();
  const int t = tid;
  float acc[16];
#pragma unroll
  for (int r = 0; r < 16; ++r) acc[r] = 0.f;
  for (int c4 = 0; c4 < 32; ++c4) {
    const int c = c4 * 4;
    float w0 = MtxT[c * 256 + t];
    float w1 = MtxT[(c + 1) * 256 + t];
    float w2 = MtxT[(c + 2) * 256 + t];
    float w3 = MtxT[(c + 3) * 256 + t];
#pragma unroll
    for (int r = 0; r < 16; ++r) {
      float4 mv = *(const float4*)&mxs[r * 128 + c];
      acc[r] += mv.x * w0 + mv.y * w1 + mv.z * w2 + mv.w * w3;
    }
  }
  float al = A_l[t], mw0 = MwT[t], mw1 = MwT[256 + t];
  float me0 = MeT[t], me1 = MeT[256 + t], me2 = MeT[512 + t], me3 = MeT[768 + t];
  float bd = bias_deg[t], mb = merge_b[t];
  float s1 = 0.f, s2 = 0.f;
#pragma unroll
  for (int r = 0; r < 16; ++r) {
    float mp = acc[r] + scal[r * 8] * al + scal[r * 8 + 1] * mw0 + scal[r * 8 + 2] * mw1
             + scal[r * 8 + 3] * me0 + scal[r * 8 + 4] * me1 + scal[r * 8 + 5] * me2
             + scal[r * 8 + 6] * me3 + scal[r * 8 + 7] * bd + mb;
    float mv = fmaxf(mp, 0.f);
    m_bf[(row0 + r) * 256 + t] = f2bf(mv);
    s1 += mv;
    s2 += mv * mv;
  }
  atomicAdd(&bnsum[t], s1);
  atomicAdd(&bnsumsq[t], s2);
}

__global__ __launch_bounds__(256) void k_bna(const float* __restrict__ bnsum,
                                             const float* __restrict__ bnsumsq,
                                             const float* __restrict__ gamma,
                                             const float* __restrict__ beta,
                                             float* __restrict__ svec,
                                             float* __restrict__ tvec) {
  int c = threadIdx.x;
  float mu = bnsum[c] * (1.f / 10240.f);
  float var = bnsumsq[c] * (1.f / 10240.f) - mu * mu;
  float s = gamma[c] * rsqrtf(var + 1e-5f);
  svec[c] = s;
  tvec[c] = beta[c] - mu * s;
}

// blocks 0..767: wbig_b (bf16 frag-linear, BN scale folded)
// blocks 768..1535: bias_big[g] = b1[g] + tvec@Wcomb[g]
__global__ __launch_bounds__(256) void k_bnbc(const float* __restrict__ Wcomb,
                                              const float* __restrict__ svec,
                                              const float* __restrict__ tvec,
                                              const float* __restrict__ b1,
                                              u16* __restrict__ wbig_b,
                                              float* __restrict__ bias_big) {
  int blk = blockIdx.x, t = threadIdx.x;
  __shared__ float red[4];
  if (blk < 768) {
    int i = blk * 256 + t;
    int j = i & 7, l = (i >> 3) & 63, kt = (i >> 9) & 7, nt = i >> 12;
    int n = nt * 16 + (l & 15);
    int k = kt * 32 + (l >> 4) * 8 + j;
    wbig_b[i] = f2bf(Wcomb[n * 256 + k] * svec[k]);
  } else {
    int gg = blk - 768;
    float part = tvec[t] * Wcomb[gg * 256 + t];
    part += __shfl_down(part, 32); part += __shfl_down(part, 16);
    part += __shfl_down(part, 8);  part += __shfl_down(part, 4);
    part += __shfl_down(part, 2);  part += __shfl_down(part, 1);
    if ((t & 63) == 0) red[t >> 6] = part;
    __syncthreads();
    if (t == 0) bias_big[gg] = b1[gg] + red[0] + red[1] + red[2] + red[3];
  }
}

// gi[N][768] = m @ Wbig^T + bias_big  (bf16 MFMA; BN+mh+Wih folded)
__global__ __launch_bounds__(256) void k_gi(const u16* __restrict__ m_bf,
                                            const u16* __restrict__ wbig_b,
                                            const float* __restrict__ bias_big,
                                            float* __restrict__ gi) {
  const int t = threadIdx.x;
  const int w = t >> 6, l = t & 63, lr = l & 15, g = l >> 4;
  const int row0 = blockIdx.x * 16;
  short8v a[8];
#pragma unroll
  for (int kt = 0; kt < 8; ++kt)
    a[kt] = *(const short8v*)&m_bf[(row0 + lr) * 256 + kt * 32 + g * 8];
  const float4v zv = {0.f, 0.f, 0.f, 0.f};
  float4v acc[12];
#pragma unroll
  for (int j = 0; j < 12; ++j) acc[j] = zv;
#pragma unroll 2
  for (int kt = 0; kt < 8; ++kt) {
#pragma unroll
    for (int j = 0; j < 12; ++j) {
      int nt = w * 12 + j;
      short8v b = *(const short8v*)&wbig_b[((nt * 8 + kt) * 64 + l) * 8];
      acc[j] = MFMA16(a[kt], b, acc[j], 0, 0, 0);
    }
  }
#pragma unroll
  for (int j = 0; j < 12; ++j) {
    int col = (w * 12 + j) * 16 + lr;
    float bb = bias_big[col];
#pragma unroll
    for (int r = 0; r < 4; ++r)
      gi[(row0 + g * 4 + r) * 768 + col] = acc[j][r] + bb;
  }
}

// ---------------------------------------------------------------------------
// Fused GRU, all 10 steps. 64 blocks x 16 rows x 8 waves (2/SIMD).
// (R11 version — proven, kept unchanged.)
// ---------------------------------------------------------------------------
__global__ __launch_bounds__(512) void k_gru_all(const float* __restrict__ gi,
                                                 const u16* __restrict__ whhb,
                                                 const float* __restrict__ bhh,
                                                 const float* __restrict__ reg_w,
                                                 const float* __restrict__ reg_b,
                                                 float* __restrict__ out) {
  __shared__ u16 hb[16 * 256];
  __shared__ float red[8][16];
  const int t = threadIdx.x;
  const int w = t >> 6, l = t & 63, lr = l & 15, g = l >> 4;
  const int row0 = blockIdx.x * 16;
  for (int i = t; i < 4096; i += 512) hb[i] = 0;
  float hp[2][4];                    // [i][r] : h(row g*4+r, col (2w+i)*16+lr)
#pragma unroll
  for (int i = 0; i < 2; ++i)
#pragma unroll
    for (int r = 0; r < 4; ++r) hp[i][r] = 0.f;
  float bh[3][2];
#pragma unroll
  for (int gate = 0; gate < 3; ++gate)
#pragma unroll
    for (int i = 0; i < 2; ++i)
      bh[gate][i] = bhh[gate * 256 + (2 * w + i) * 16 + lr];
  float racc[4] = {0.f, 0.f, 0.f, 0.f};

  for (int s = 0; s < 10; ++s) {
    __syncthreads();                 // hb (init or prev-step writes) visible
    const float4v zv = {0.f, 0.f, 0.f, 0.f};
    float4v acc[3][2];
#pragma unroll
    for (int gate = 0; gate < 3; ++gate)
#pragma unroll
      for (int i = 0; i < 2; ++i) acc[gate][i] = zv;
#pragma unroll
    for (int kt = 0; kt < 8; ++kt) {
      int kb = kt * 4 + g;
      int bb = kb ^ (lr & 7);
      short8v a = *(const short8v*)&hb[lr * 256 + bb * 8];
#pragma unroll
      for (int gate = 0; gate < 3; ++gate)
#pragma unroll
        for (int i = 0; i < 2; ++i) {
          int nt = gate * 16 + 2 * w + i;
          short8v b = *(const short8v*)&whhb[((nt * 8 + kt) * 64 + l) * 8];
          acc[gate][i] = MFMA16(a, b, acc[gate][i], 0, 0, 0);
        }
    }
    __syncthreads();                 // all hb reads done before overwrite
#pragma unroll
    for (int i = 0; i < 2; ++i) {
      int c = (2 * w + i) * 16 + lr;
      float rwv = reg_w[s * 256 + c];
#pragma unroll
      for (int r = 0; r < 4; ++r) {
        int node = (row0 + g * 4 + r) * 10 + s;
        float gir = gi[node * 768 + c];
        float giz = gi[node * 768 + 256 + c];
        float gin = gi[node * 768 + 512 + c];
        float ghr = acc[0][i][r] + bh[0][i];
        float ghz = acc[1][i][r] + bh[1][i];
        float ghn = acc[2][i][r] + bh[2][i];
        float rg = 1.f / (1.f + expf(-(gir + ghr)));
        float zg = 1.f / (1.f + expf(-(giz + ghz)));
        float ng = tanhf(gin + rg * ghn);
        float hn = (1.f - zg) * ng + zg * hp[i][r];
        hp[i][r] = hn;
        racc[r] += hn * rwv;
        int m = g * 4 + r;
        int bb2 = (c >> 3) ^ (m & 7);
        hb[m * 256 + bb2 * 8 + (c & 7)] = f2bf(hn);
      }
    }
  }
#pragma unroll
  for (int r = 0; r < 4; ++r) {
    float v = racc[r];
    v += __shfl_xor(v, 1); v += __shfl_xor(v, 2);
    v += __shfl_xor(v, 4); v += __shfl_xor(v, 8);
    racc[r] = v;
  }
  if (lr == 0) {
#pragma unroll
    for (int r = 0; r < 4; ++r) red[w][g * 4 + r] = racc[r];
  }
  __syncthreads();
  if (t < 16) {
    float sum = reg_b[0];
#pragma unroll
    for (int w8 = 0; w8 < 8; ++w8) sum += red[w8][t];
    out[row0 + t] = sum;
  }
}

extern "C" void kernel_launch(void* const* d_in, const int* in_sizes, int n_in,
                              void* d_out, int out_size, void* d_ws, size_t ws_size,
                              hipStream_t stream) {
  (void)in_sizes; (void)n_in; (void)out_size; (void)ws_size;
  const float* lags      = (const float*)d_in[0];
  const float* weather   = (const float*)d_in[1];
  const float* event     = (const float*)d_in[2];
  const int*   text      = (const int*)d_in[3];
  const float* emb       = (const float*)d_in[4];
  const float* conv3_w   = (const float*)d_in[5];
  const float* conv3_b   = (const float*)d_in[6];
  const float* conv4_w   = (const float*)d_in[7];
  const float* conv4_b   = (const float*)d_in[8];
  const float* lags_w    = (const float*)d_in[9];
  const float* lags_b    = (const float*)d_in[10];
  const float* weather_w = (const float*)d_in[11];
  const float* weather_b = (const float*)d_in[12];
  const float* event_w   = (const float*)d_in[13];
  const float* event_b   = (const float*)d_in[14];
  const float* text_w    = (const float*)d_in[15];
  const float* text_b    = (const float*)d_in[16];
  const float* merge_w   = (const float*)d_in[17];
  const float* merge_b   = (const float*)d_in[18];
  const float* bn_gamma  = (const float*)d_in[19];
  const float* bn_beta   = (const float*)d_in[20];
  const float* mh_w      = (const float*)d_in[21];
  const float* mh_b      = (const float*)d_in[22];
  const float* gru_wih   = (const float*)d_in[23];
  const float* gru_whh   = (const float*)d_in[24];
  const float* gru_bih   = (const float*)d_in[25];
  const float* gru_bhh   = (const float*)d_in[26];
  const float* reg_w     = (const float*)d_in[27];
  const float* reg_b     = (const float*)d_in[28];
  float* out = (float*)d_out;

  float* p = (float*)d_ws;
  float* bnsum    = p; p += 256;            // zeroed
  float* bnsumsq  = p; p += 256;            // zeroed
  float* mx       = p; p += 10240 * 128;
  u16*   m_bf     = (u16*)p; p += 10240 * 128;   // 10240*256 u16
  float* gi       = p; p += 10240 * 768;
  u16*   w3b      = (u16*)p; p += 12288;    // 24576 u16
  u16*   w4b      = (u16*)p; p += 32768;    // 65536 u16
  u16*   whhb     = (u16*)p; p += 98304;    // 196608 u16
  u16*   wbig_b   = (u16*)p; p += 98304;    // 196608 u16
  float* Wcomb    = p; p += 196608;
  float* MtxT     = p; p += 32768;
  float* A_l      = p; p += 256;
  float* MwT      = p; p += 512;
  float* MeT      = p; p += 1024;
  float* bias_deg = p; p += 256;
  float* b1       = p; p += 768;
  float* bias_big = p; p += 768;
  float* svec     = p; p += 256;
  float* tvec     = p; p += 256;
  // mwT [1024][256] ALIASES mx: k_tr writes (launch 5), k_pmerge reads
  // (launch 7), k_textcnn's first mx write is launch 8 — same stream, so
  // lifetimes are disjoint. Footprint stays at R2's proven 43.85MB.
  float* mwT      = mx;

  k_zero<<<dim3(2), dim3(256), 0, stream>>>(bnsum, 512);
  k_repb3<<<dim3(96), dim3(256), 0, stream>>>(conv3_w, w3b);
  k_repb4<<<dim3(256), dim3(256), 0, stream>>>(conv4_w, w4b);
  k_repwhh<<<dim3(768), dim3(256), 0, stream>>>(gru_whh, whhb);
  k_tr<<<dim3(32, 8), dim3(256), 0, stream>>>(merge_w, mwT);
  k_pcomb<<<dim3(96), dim3(256), 0, stream>>>(gru_wih, mh_w, mh_b, gru_bih, Wcomb, b1);
  k_pmerge<<<dim3(129), dim3(256), 0, stream>>>(mwT, text_w, lags_w, weather_w, event_w,
                                                lags_b, weather_b, event_b, text_b,
                                                MtxT, A_l, MwT, MeT, bias_deg);
  k_textcnn<<<dim3(10240), dim3(256), 0, stream>>>(text, emb, w3b, conv3_b, w4b, conv4_b, mx);
  k_merge<<<dim3(640), dim3(256), 0, stream>>>(mx, lags, weather, event, MtxT, A_l, MwT, MeT,
                                               bias_deg, merge_b, m_bf, bnsum, bnsumsq);
  k_bna<<<dim3(1), dim3(256), 0, stream>>>(bnsum, bnsumsq, bn_gamma, bn_beta, svec, tvec);
  k_bnbc<<<dim3(1536), dim3(256), 0, stream>>>(Wcomb, svec, tvec, b1, wbig_b, bias_big);
  k_gi<<<dim3(640), dim3(256), 0, stream>>>(m_bf, wbig_b, bias_big, gi);
  k_gru_all<<<dim3(64), dim3(512), 0, stream>>>(gi, whhb, gru_bhh, reg_w, reg_b, out);
}